// Round 9
// baseline (604.247 us; speedup 1.0000x reference)
//
#include <hip/hip_runtime.h>
#include <hip/hip_bf16.h>
#include <cstdint>
#include <cstddef>

typedef __hip_bfloat16 bf16;
typedef unsigned short ushort;
typedef __attribute__((ext_vector_type(8))) short bf16x8;
typedef __attribute__((ext_vector_type(4))) float f32x4;

#define HDIM 256
#define NVOCAB 26
#define STR 264

// ---- workspace layout (float offsets) ----
#define OFF_BSUM  16
#define OFF_Z1    (OFF_BSUM+1024)
#define OFF_HH1   (OFF_Z1+1024)
#define OFF_H1    (OFF_HH1+1024)
#define OFF_C1    (OFF_H1+256)
#define OFF_WCH1  (OFF_C1+256)
#define OFF_BTF   (OFF_WCH1+256)
#define OFF_EWC   (OFF_BTF+256)          // [26][256] f32
#define OFF_P8    (OFF_EWC+6656)         // [26][1024] f32
#define OFF_SCB   (OFF_P8+26624)         // [32][256] ushort (scomb bf16 rows)
#define OFF_O8B   (OFF_SCB+4096)         // [32][256] ushort (out8 bf16 rows)
#define OFF_FRAG  (OFF_O8B+4096)         // ushort frag tables
#define OFF_SLABS (OFF_FRAG+327680)

__device__ __forceinline__ float sigmf(float x){ return 1.0f/(1.0f+__expf(-x)); }
__device__ __forceinline__ float tanhfast(float x){ return 1.0f - 2.0f/(__expf(2.0f*x)+1.0f); }
__device__ __forceinline__ ushort f2b(float x){ bf16 h = __float2bfloat16(x); return *(ushort*)&h; }
__device__ __forceinline__ float ldin(const void* p, int i, int f32){
  if (f32) return ((const float*)p)[i];
  unsigned int w = ((unsigned int)((const ushort*)p)[i]) << 16;
  return __uint_as_float(w);
}
__device__ __forceinline__ void ld8(const void* p, int i, int f32, float* o){
  if (f32){
    float4 a = *(const float4*)((const float*)p + i);
    float4 b = *(const float4*)((const float*)p + i + 4);
    o[0]=a.x;o[1]=a.y;o[2]=a.z;o[3]=a.w;o[4]=b.x;o[5]=b.y;o[6]=b.z;o[7]=b.w;
  } else {
    uint4 u = *(const uint4*)((const ushort*)p + i);
    unsigned w0=u.x,w1=u.y,w2=u.z,w3=u.w;
    o[0]=__uint_as_float(w0<<16); o[1]=__uint_as_float(w0&0xFFFF0000u);
    o[2]=__uint_as_float(w1<<16); o[3]=__uint_as_float(w1&0xFFFF0000u);
    o[4]=__uint_as_float(w2<<16); o[5]=__uint_as_float(w2&0xFFFF0000u);
    o[6]=__uint_as_float(w3<<16); o[7]=__uint_as_float(w3&0xFFFF0000u);
  }
}

__global__ void init_kernel(int* wsI){ if (threadIdx.x<4) wsI[threadIdx.x]=0; }

__global__ __launch_bounds__(256) void detect_kernel(int* wsI, const uint4* wih4){
  int c=0;
  for (int i = blockIdx.x*blockDim.x + threadIdx.x; i < 32768; i += gridDim.x*blockDim.x){
    uint4 u = wih4[i];
    unsigned w[4] = {u.x,u.y,u.z,u.w};
    #pragma unroll
    for (int j=0;j<4;j++){
      if ((w[j] & 0x7F80u) == 0x7F80u) c++;
      if ((w[j] & 0x7F800000u) == 0x7F800000u) c++;
    }
  }
  #pragma unroll
  for (int o=32;o>0;o>>=1) c += __shfl_xor(c,o,64);
  if ((threadIdx.x&63)==0 && c) atomicAdd(&wsI[1], c);
}

__global__ __launch_bounds__(256) void z1_kernel(
    float* __restrict__ wsf, const void* W_ih, const void* b_ih, const void* b_hh,
    const void* bt, const void* linit)
{
  const int f32 = ((const int*)wsf)[1] != 0;
  __shared__ float sx[256];
  int tid = threadIdx.x;
  int r = blockIdx.x*256 + tid;
  sx[tid] = ldin(linit, tid, f32);
  __syncthreads();
  float a = ldin(b_ih, r, f32) + ldin(b_hh, r, f32);
  wsf[OFF_BSUM + r] = a;
  float z = a;
  #pragma unroll 8
  for (int k=0;k<256;k+=8){
    float w[8]; ld8(W_ih, r*256+k, f32, w);
    #pragma unroll
    for (int j=0;j<8;j++) z += w[j]*sx[k+j];
  }
  wsf[OFF_Z1 + r] = z;
  if (blockIdx.x==0) wsf[OFF_BTF + tid] = ldin(bt, tid, f32);
}

__global__ __launch_bounds__(256) void h1_kernel(float* __restrict__ wsf){
  int e = threadIdx.x;
  float zi = wsf[OFF_Z1+e], zg = wsf[OFF_Z1+512+e], zo = wsf[OFF_Z1+768+e];
  float c1 = sigmf(zi)*tanhfast(zg);
  float h1 = sigmf(zo)*tanhfast(c1);
  wsf[OFF_H1+e]=h1; wsf[OFF_C1+e]=c1;
}

// blocks 0..3: hh1 rows; block 4: wch1 + scomb bf16 rows (needs EWC done)
__global__ __launch_bounds__(256) void hh1_kernel(float* __restrict__ wsf, const void* W_hh, const void* Wc){
  const int f32 = ((const int*)wsf)[1] != 0;
  __shared__ float sh1[256];
  int tid = threadIdx.x;
  sh1[tid] = wsf[OFF_H1+tid];
  __syncthreads();
  if (blockIdx.x < 4){
    int r = blockIdx.x*256 + tid;
    float z = wsf[OFF_BSUM + r];
    #pragma unroll 8
    for (int k=0;k<256;k+=8){
      float w[8]; ld8(W_hh, r*256+k, f32, w);
      #pragma unroll
      for (int j=0;j<8;j++) z += w[j]*sh1[k+j];
    }
    wsf[OFF_HH1 + r] = z;
  } else {
    float a = 0.f;
    #pragma unroll 8
    for (int k=0;k<256;k+=8){
      float w[8]; ld8(Wc, tid*512+k, f32, w);
      #pragma unroll
      for (int j=0;j<8;j++) a += w[j]*sh1[k+j];
    }
    wsf[OFF_WCH1 + tid] = a;
    ushort* SCB = (ushort*)(wsf + OFF_SCB);
    #pragma unroll 1
    for (int v32=0; v32<32; v32++){
      int v = v32 < NVOCAB ? v32 : NVOCAB-1;
      SCB[v32*256 + tid] = f2b(a + wsf[OFF_EWC + v*256 + tid]);
    }
  }
}

__global__ __launch_bounds__(256) void ewc_kernel(
    float* __restrict__ wsf, const void* Wc, const void* bc, const void* emb)
{
  const int f32 = ((const int*)wsf)[1] != 0;
  int v = blockIdx.x, i = threadIdx.x;
  __shared__ float se[256];
  se[i] = ldin(emb, v*256+i, f32);
  __syncthreads();
  float a = ldin(bc, i, f32);
  #pragma unroll 8
  for (int k=0;k<256;k+=8){
    float w[8]; ld8(Wc, i*512+256+k, f32, w);
    #pragma unroll
    for (int j=0;j<8;j++) a += w[j]*se[k+j];
  }
  wsf[OFF_EWC + v*256 + i] = a;
}

// A-fragment tables: chunk=(mt*8+ks), lane L, j: m=mt*16+(L&15), k=ks*32+(L>>4)*8+j
__global__ __launch_bounds__(256) void prep_kernel(
    float* __restrict__ wsf, const void* W_ih, const void* W_hh, const void* Wc, const void* Wt)
{
  const int f32 = ((const int*)wsf)[1] != 0;
  ushort* FWIH = (ushort*)(wsf + OFF_FRAG);
  ushort* FWHH = FWIH + 262144;
  ushort* FWC1 = FWHH + 262144;
  ushort* FWT  = FWC1 + 65536;
  int stride = gridDim.x*blockDim.x;
  int t0 = blockIdx.x*blockDim.x + threadIdx.x;
  for (int idx=t0; idx<262144; idx+=stride){
    int c = idx>>9, r = idx&511, L = r>>3, j = r&7;
    int mt = c>>3, ks = c&7;
    int m = (mt<<4) | (L&15);
    int k = (ks<<5) + ((L>>4)<<3) + j;
    FWIH[idx] = f2b(ldin(W_ih, m*256+k, f32));
    FWHH[idx] = f2b(ldin(W_hh, m*256+k, f32));
  }
  for (int idx=t0; idx<65536; idx+=stride){
    int c = idx>>9, r = idx&511, L = r>>3, j = r&7;
    int mt = c>>3, ks = c&7;
    int m = (mt<<4) | (L&15);
    int k = (ks<<5) + ((L>>4)<<3) + j;
    FWC1[idx] = f2b(ldin(Wc, m*512+k, f32));
    FWT [idx] = f2b(ldin(Wt, m*256+k, f32));
  }
}

// ---- tag8: tag = Wt@scomb + bt, log-softmax, out8 bf16 rows (26 vocab) ----
__global__ __launch_bounds__(256) void tag8_kernel(float* __restrict__ wsf){
  __shared__ float wred[4][16];
  const int tid=threadIdx.x, wv=tid>>6, lane=tid&63, ln15=lane&15, quad=lane>>4;
  const int nt = blockIdx.x;
  const ushort* FWT = (const ushort*)(wsf + OFF_FRAG) + 262144 + 262144 + 65536;
  const ushort* SCB = (const ushort*)(wsf + OFF_SCB);
  ushort* O8B = (ushort*)(wsf + OFF_O8B);
  const int row = nt*16 + ln15;

  f32x4 tg[4];
  #pragma unroll 1
  for (int p=0; p<4; p++){
    const int mt = wv*4 + p;
    tg[p] = (f32x4){0.f,0.f,0.f,0.f};
    #pragma unroll
    for (int ks=0; ks<8; ks++){
      bf16x8 a = *(const bf16x8*)&FWT[((mt*8+ks)<<9) + (lane<<3)];
      bf16x8 b = *(const bf16x8*)&SCB[row*256 + ks*32 + quad*8];
      tg[p] = __builtin_amdgcn_mfma_f32_16x16x32_bf16(a, b, tg[p], 0,0,0);
    }
    float4 bt4 = *(const float4*)&wsf[OFF_BTF + mt*16 + quad*4];
    #pragma unroll
    for (int r=0; r<4; r++) tg[p][r] += ((const float*)&bt4)[r];
  }

  float mx = -3.0e38f;
  #pragma unroll
  for (int p=0; p<4; p++)
    #pragma unroll
    for (int r=0; r<4; r++) mx = fmaxf(mx, tg[p][r]);
  mx = fmaxf(mx, __shfl_xor(mx, 16, 64));
  mx = fmaxf(mx, __shfl_xor(mx, 32, 64));
  wred[wv][ln15] = mx;
  __syncthreads();
  float gmx = fmaxf(fmaxf(wred[0][ln15], wred[1][ln15]), fmaxf(wred[2][ln15], wred[3][ln15]));
  __syncthreads();
  float s = 0.f;
  #pragma unroll
  for (int p=0; p<4; p++)
    #pragma unroll
    for (int r=0; r<4; r++) s += __expf(tg[p][r] - gmx);
  s += __shfl_xor(s, 16, 64);
  s += __shfl_xor(s, 32, 64);
  wred[wv][ln15] = s;
  __syncthreads();
  float gs = (wred[0][ln15]+wred[1][ln15]) + (wred[2][ln15]+wred[3][ln15]);
  float lz = gmx + __logf(gs);

  #pragma unroll
  for (int p=0; p<4; p++){
    int m = (wv*4+p)*16 + quad*4;
    ushort ob[4];
    #pragma unroll
    for (int r=0; r<4; r++) ob[r] = f2b(tg[p][r] - lz);
    uint2 uu;
    uu.x = (unsigned)ob[0] | ((unsigned)ob[1]<<16);
    uu.y = (unsigned)ob[2] | ((unsigned)ob[3]<<16);
    *(uint2*)&O8B[row*256 + m] = uu;
  }
}

// ---- p8: P8[v] = W_ih @ out8[v] via MFMA; grid = 2x16 blocks of 64 ----
__global__ __launch_bounds__(64) void p8_kernel(float* __restrict__ wsf){
  const int nt = blockIdx.x >> 4, eb = blockIdx.x & 15;
  const int lane = threadIdx.x, ln15 = lane & 15, quad = lane >> 4;
  const ushort* FWIH = (const ushort*)(wsf + OFF_FRAG);
  const ushort* O8B  = (const ushort*)(wsf + OFF_O8B);
  const int row = nt*16 + ln15;

  f32x4 acc[4];
  #pragma unroll
  for (int g=0; g<4; g++) acc[g] = (f32x4){0.f,0.f,0.f,0.f};
  #pragma unroll
  for (int ks=0; ks<8; ks++){
    bf16x8 b = *(const bf16x8*)&O8B[row*256 + ks*32 + quad*8];
    #pragma unroll
    for (int g=0; g<4; g++){
      int mt = g*16 + eb;
      bf16x8 a = *(const bf16x8*)&FWIH[((mt*8+ks)<<9) + (lane<<3)];
      acc[g] = __builtin_amdgcn_mfma_f32_16x16x32_bf16(a, b, acc[g], 0,0,0);
    }
  }
  if (row < NVOCAB){
    #pragma unroll
    for (int g=0; g<4; g++)
      *(float4*)&wsf[OFF_P8 + row*1024 + g*256 + eb*16 + quad*4] =
        (float4){acc[g][0], acc[g][1], acc[g][2], acc[g][3]};
  }
}

// ---- fused level kernel for big levels (7,6): 1024 threads = 16 waves ----
// amdgpu_waves_per_eu(4,4): pin exactly 4 waves/EU (1 block/CU) -> 128-VGPR
// budget. (__launch_bounds__(1024,4) left VGPR at 64 and spilled ~200MB.)
template<int NT, bool GATHER>
__global__ __launch_bounds__(1024) __attribute__((amdgpu_waves_per_eu(4,4)))
void level_kernel(
    const float* __restrict__ wsf, const ushort* __restrict__ OutPrev,
    const int* __restrict__ idents, int offL, int offC, int nNodes, int nChild,
    ushort* __restrict__ OutNext)
{
  constexpr int NN = NT*16;
  __shared__ __align__(16) ushort Hlds[2][NN*STR];
  __shared__ __align__(16) ushort Xlds[GATHER ? 16 : NN*STR];
  __shared__ float wred[16][NN];
  __shared__ int sid[NN];
  __shared__ int sid4[GATHER ? NN*4 : 4];

  const int tid  = threadIdx.x;
  const int wv   = tid >> 6;
  const int lane = tid & 63;
  const int ln15 = lane & 15;
  const int quad = lane >> 4;
  const int j0   = blockIdx.x * NN;

  const ushort* FWIH = (const ushort*)(wsf + OFF_FRAG);
  const ushort* FWHH = FWIH + 262144;
  const ushort* FWC1 = FWHH + 262144;
  const ushort* FWT  = FWC1 + 65536;
  const float*  P8   = wsf + OFF_P8;
  const float*  EWcP = wsf + OFF_EWC;

  if (tid<NN){ int nd=j0+tid; if (nd>=nNodes) nd=nNodes-1; sid[tid]=idents[offL+nd]; }
  if (GATHER){
    for (int i=tid; i<NN*4; i+=1024){
      int ci = j0*4 + i; if (ci >= nChild) ci = nChild-1;
      sid4[i] = idents[offC + ci];
    }
  }

  f32x4 creg[NT];

  #pragma unroll 1
  for (int t=1; t<=4; t++){
    if (!GATHER){
      for (int i=tid; i<NN*32; i+=1024){
        int n = i>>5, off = i&31;
        int node = j0+n; if (node>=nNodes) node=nNodes-1;
        uint4 v = ((const uint4*)OutPrev)[((size_t)node*4 + (t-1))*32 + off];
        *(uint4*)&Xlds[n*STR + off*8] = v;
      }
    }
    __syncthreads();
    const int rb = (t-1)&1, wb = t&1;

    f32x4 acc[4][NT];
    #pragma unroll
    for (int g=0; g<4; g++)
      #pragma unroll
      for (int n=0; n<NT; n++) acc[g][n] = (f32x4){0.f,0.f,0.f,0.f};

    if (t>=2){
      #pragma unroll
      for (int ks=0; ks<8; ks++){
        bf16x8 bh[NT];
        #pragma unroll
        for (int n=0; n<NT; n++)
          bh[n] = *(const bf16x8*)&Hlds[rb][(n*16+ln15)*STR + ks*32 + quad*8];
        #pragma unroll
        for (int g=0; g<4; g++){
          int mt = g*16 + wv;
          bf16x8 a = *(const bf16x8*)&FWHH[((mt*8+ks)<<9) + (lane<<3)];
          #pragma unroll
          for (int n=0; n<NT; n++)
            acc[g][n] = __builtin_amdgcn_mfma_f32_16x16x32_bf16(a, bh[n], acc[g][n], 0,0,0);
        }
      }
    }
    if (!GATHER){
      #pragma unroll
      for (int ks=0; ks<8; ks++){
        bf16x8 bx[NT];
        #pragma unroll
        for (int n=0; n<NT; n++)
          bx[n] = *(const bf16x8*)&Xlds[(n*16+ln15)*STR + ks*32 + quad*8];
        #pragma unroll
        for (int g=0; g<4; g++){
          int mt = g*16 + wv;
          bf16x8 a = *(const bf16x8*)&FWIH[((mt*8+ks)<<9) + (lane<<3)];
          #pragma unroll
          for (int n=0; n<NT; n++)
            acc[g][n] = __builtin_amdgcn_mfma_f32_16x16x32_bf16(a, bx[n], acc[g][n], 0,0,0);
        }
      }
    }

    // fold base bias into acc (one float4 live at a time)
    const float* baseP = wsf + ((t==1) ? OFF_HH1 : OFF_BSUM);
    const int eb = wv*16;
    #pragma unroll
    for (int g=0; g<4; g++){
      float4 bg = *(const float4*)&baseP[g*256 + eb + quad*4];
      #pragma unroll
      for (int n=0; n<NT; n++){
        acc[g][n][0]+=bg.x; acc[g][n][1]+=bg.y; acc[g][n][2]+=bg.z; acc[g][n][3]+=bg.w;
      }
    }
    // fold gather input into acc
    if (GATHER){
      #pragma unroll
      for (int n=0; n<NT; n++){
        const float* pg = P8 + (size_t)sid4[(n*16+ln15)*4 + (t-1)]*1024;
        #pragma unroll
        for (int g=0; g<4; g++){
          float4 xg = *(const float4*)&pg[g*256 + eb + quad*4];
          acc[g][n][0]+=xg.x; acc[g][n][1]+=xg.y; acc[g][n][2]+=xg.z; acc[g][n][3]+=xg.w;
        }
      }
    }
    // gate math
    #pragma unroll
    for (int n=0; n<NT; n++){
      f32x4 cp;
      if (t==1){
        float4 cc = *(const float4*)&wsf[OFF_C1 + eb + quad*4];
        cp = (f32x4){cc.x,cc.y,cc.z,cc.w};
      } else cp = creg[n];
      ushort hb[4];
      #pragma unroll
      for (int r=0; r<4; r++){
        float cn = sigmf(acc[1][n][r])*cp[r] + sigmf(acc[0][n][r])*tanhfast(acc[2][n][r]);
        creg[n][r] = cn;
        hb[r] = f2b(sigmf(acc[3][n][r])*tanhfast(cn));
      }
      uint2 uu;
      uu.x = (unsigned)hb[0] | ((unsigned)hb[1]<<16);
      uu.y = (unsigned)hb[2] | ((unsigned)hb[3]<<16);
      *(uint2*)&Hlds[wb][(n*16+ln15)*STR + eb + quad*4] = uu;
    }
    __syncthreads();
  }

  // combined = Wc1@h + EWc[id]
  {
    f32x4 ac[NT];
    #pragma unroll
    for (int n=0; n<NT; n++) ac[n] = (f32x4){0.f,0.f,0.f,0.f};
    #pragma unroll
    for (int ks=0; ks<8; ks++){
      bf16x8 a = *(const bf16x8*)&FWC1[((wv*8+ks)<<9) + (lane<<3)];
      #pragma unroll
      for (int n=0; n<NT; n++){
        bf16x8 b = *(const bf16x8*)&Hlds[0][(n*16+ln15)*STR + ks*32 + quad*8];
        ac[n] = __builtin_amdgcn_mfma_f32_16x16x32_bf16(a, b, ac[n], 0,0,0);
      }
    }
    #pragma unroll
    for (int n=0; n<NT; n++){
      float4 ew = *(const float4*)&EWcP[(size_t)sid[n*16+ln15]*256 + wv*16 + quad*4];
      ushort cb[4];
      #pragma unroll
      for (int r=0; r<4; r++) cb[r] = f2b(ac[n][r] + ((const float*)&ew)[r]);
      uint2 uu;
      uu.x = (unsigned)cb[0] | ((unsigned)cb[1]<<16);
      uu.y = (unsigned)cb[2] | ((unsigned)cb[3]<<16);
      *(uint2*)&Hlds[1][(n*16+ln15)*STR + wv*16 + quad*4] = uu;
    }
  }
  __syncthreads();

  // tag = Wt@combined + bt
  f32x4 tg[NT];
  {
    #pragma unroll
    for (int n=0; n<NT; n++) tg[n] = (f32x4){0.f,0.f,0.f,0.f};
    #pragma unroll
    for (int ks=0; ks<8; ks++){
      bf16x8 a = *(const bf16x8*)&FWT[((wv*8+ks)<<9) + (lane<<3)];
      #pragma unroll
      for (int n=0; n<NT; n++){
        bf16x8 b = *(const bf16x8*)&Hlds[1][(n*16+ln15)*STR + ks*32 + quad*8];
        tg[n] = __builtin_amdgcn_mfma_f32_16x16x32_bf16(a, b, tg[n], 0,0,0);
      }
    }
    float4 bt4 = *(const float4*)&wsf[OFF_BTF + wv*16 + quad*4];
    #pragma unroll
    for (int n=0; n<NT; n++)
      #pragma unroll
      for (int r=0; r<4; r++) tg[n][r] += ((const float*)&bt4)[r];
  }

  float gmx[NT], gs[NT];
  {
    #pragma unroll
    for (int n=0; n<NT; n++){
      float mx = fmaxf(fmaxf(tg[n][0],tg[n][1]), fmaxf(tg[n][2],tg[n][3]));
      mx = fmaxf(mx, __shfl_xor(mx, 16, 64));
      mx = fmaxf(mx, __shfl_xor(mx, 32, 64));
      wred[wv][n*16+ln15] = mx;
    }
    __syncthreads();
    #pragma unroll
    for (int n=0; n<NT; n++){
      float m = wred[0][n*16+ln15];
      #pragma unroll
      for (int w=1; w<16; w++) m = fmaxf(m, wred[w][n*16+ln15]);
      gmx[n] = m;
    }
    __syncthreads();
    #pragma unroll
    for (int n=0; n<NT; n++){
      float s = __expf(tg[n][0]-gmx[n]) + __expf(tg[n][1]-gmx[n])
              + __expf(tg[n][2]-gmx[n]) + __expf(tg[n][3]-gmx[n]);
      s += __shfl_xor(s, 16, 64);
      s += __shfl_xor(s, 32, 64);
      wred[wv][n*16+ln15] = s;
    }
    __syncthreads();
    #pragma unroll
    for (int n=0; n<NT; n++){
      float s = 0.f;
      #pragma unroll
      for (int w=0; w<16; w++) s += wred[w][n*16+ln15];
      gs[n] = s;
    }
  }

  #pragma unroll
  for (int n=0; n<NT; n++){
    int node = j0 + n*16 + ln15;
    if (node >= nNodes) continue;
    float lz = gmx[n] + __logf(gs[n]);
    ushort ob[4];
    #pragma unroll
    for (int r=0; r<4; r++) ob[r] = f2b(tg[n][r] - lz);
    uint2 uu;
    uu.x = (unsigned)ob[0] | ((unsigned)ob[1]<<16);
    uu.y = (unsigned)ob[2] | ((unsigned)ob[3]<<16);
    *(uint2*)&OutNext[(size_t)node*256 + wv*16 + quad*4] = uu;
  }
}

// ---- one LSTM t-step for small levels: M-parallel across the grid ----
template<bool FIRST>
__global__ __launch_bounds__(64) void step_kernel(
    const float* __restrict__ wsf, const ushort* __restrict__ OutPrev,
    const ushort* __restrict__ Hin, ushort* __restrict__ Hout,
    float* __restrict__ Cbuf, int nNodes, int tm1)
{
  const int nt   = blockIdx.x >> 4;
  const int eb   = blockIdx.x & 15;
  const int lane = threadIdx.x;
  const int ln15 = lane & 15;
  const int quad = lane >> 4;

  const ushort* FWIH = (const ushort*)(wsf + OFF_FRAG);
  const ushort* FWHH = FWIH + 262144;

  int node = nt*16 + ln15; if (node >= nNodes) node = nNodes-1;
  const int rowX = (node*4 + tm1) * 256;
  const int rowH = node * 256;

  f32x4 acc[4];
  #pragma unroll
  for (int g=0; g<4; g++) acc[g] = (f32x4){0.f,0.f,0.f,0.f};

  #pragma unroll
  for (int ks=0; ks<8; ks++){
    bf16x8 bx = *(const bf16x8*)&OutPrev[rowX + ks*32 + quad*8];
    bf16x8 bh;
    if (!FIRST) bh = *(const bf16x8*)&Hin[rowH + ks*32 + quad*8];
    #pragma unroll
    for (int g=0; g<4; g++){
      int mt = g*16 + eb;
      bf16x8 a = *(const bf16x8*)&FWIH[((mt*8+ks)<<9) + (lane<<3)];
      acc[g] = __builtin_amdgcn_mfma_f32_16x16x32_bf16(a, bx, acc[g], 0,0,0);
      if (!FIRST){
        bf16x8 a2 = *(const bf16x8*)&FWHH[((mt*8+ks)<<9) + (lane<<3)];
        acc[g] = __builtin_amdgcn_mfma_f32_16x16x32_bf16(a2, bh, acc[g], 0,0,0);
      }
    }
  }

  const float* baseP = wsf + (FIRST ? OFF_HH1 : OFF_BSUM);
  const int e0 = eb*16 + quad*4;
  float4 b0 = *(const float4*)&baseP[       e0];
  float4 b1 = *(const float4*)&baseP[ 256 + e0];
  float4 b2 = *(const float4*)&baseP[ 512 + e0];
  float4 b3 = *(const float4*)&baseP[ 768 + e0];
  float4 cp;
  if (FIRST) cp = *(const float4*)&wsf[OFF_C1 + e0];
  else       cp = *(const float4*)&Cbuf[rowH + e0];

  float cn4[4]; ushort hb[4];
  #pragma unroll
  for (int r=0; r<4; r++){
    float zi = acc[0][r] + ((const float*)&b0)[r];
    float zf = acc[1][r] + ((const float*)&b1)[r];
    float zg = acc[2][r] + ((const float*)&b2)[r];
    float zo = acc[3][r] + ((const float*)&b3)[r];
    float cn = sigmf(zf)*((const float*)&cp)[r] + sigmf(zi)*tanhfast(zg);
    cn4[r] = cn;
    hb[r] = f2b(sigmf(zo)*tanhfast(cn));
  }
  *(float4*)&Cbuf[rowH + e0] = (float4){cn4[0],cn4[1],cn4[2],cn4[3]};
  uint2 uu;
  uu.x = (unsigned)hb[0] | ((unsigned)hb[1]<<16);
  uu.y = (unsigned)hb[2] | ((unsigned)hb[3]<<16);
  *(uint2*)&Hout[rowH + e0] = uu;
}

// ---- epilogue for small levels: combine -> tag -> log-softmax -> out ----
template<bool FINAL>
__global__ __launch_bounds__(256) void fin_kernel(
    const float* __restrict__ wsf, const ushort* __restrict__ Hfin,
    const int* __restrict__ idents, int offL, int nNodes,
    ushort* __restrict__ OutNext, void* __restrict__ dout)
{
  __shared__ __align__(16) ushort Clds[16*STR];
  __shared__ float wred[4][16];
  const int tid  = threadIdx.x;
  const int wv   = tid >> 6;
  const int lane = tid & 63;
  const int ln15 = lane & 15;
  const int quad = lane >> 4;
  const int nt   = blockIdx.x;

  const ushort* FWIH = (const ushort*)(wsf + OFF_FRAG);
  const ushort* FWC1 = FWIH + 262144 + 262144;
  const ushort* FWT  = FWC1 + 65536;
  const float*  EWcP = wsf + OFF_EWC;

  int node = nt*16 + ln15; if (node >= nNodes) node = nNodes-1;
  const int myid = idents[offL + node];
  const int rowH = node * 256;

  #pragma unroll 1
  for (int p=0; p<4; p++){
    const int mt = wv*4 + p;
    f32x4 ac = (f32x4){0.f,0.f,0.f,0.f};
    #pragma unroll
    for (int ks=0; ks<8; ks++){
      bf16x8 a = *(const bf16x8*)&FWC1[((mt*8+ks)<<9) + (lane<<3)];
      bf16x8 b = *(const bf16x8*)&Hfin[rowH + ks*32 + quad*8];
      ac = __builtin_amdgcn_mfma_f32_16x16x32_bf16(a, b, ac, 0,0,0);
    }
    float4 ew = *(const float4*)&EWcP[(size_t)myid*256 + mt*16 + quad*4];
    ushort cb[4];
    #pragma unroll
    for (int r=0; r<4; r++) cb[r] = f2b(ac[r] + ((const float*)&ew)[r]);
    uint2 uu;
    uu.x = (unsigned)cb[0] | ((unsigned)cb[1]<<16);
    uu.y = (unsigned)cb[2] | ((unsigned)cb[3]<<16);
    *(uint2*)&Clds[ln15*STR + mt*16 + quad*4] = uu;
  }
  __syncthreads();

  f32x4 tg[4];
  #pragma unroll 1
  for (int p=0; p<4; p++){
    const int mt = wv*4 + p;
    tg[p] = (f32x4){0.f,0.f,0.f,0.f};
    #pragma unroll
    for (int ks=0; ks<8; ks++){
      bf16x8 a = *(const bf16x8*)&FWT[((mt*8+ks)<<9) + (lane<<3)];
      bf16x8 b = *(const bf16x8*)&Clds[ln15*STR + ks*32 + quad*8];
      tg[p] = __builtin_amdgcn_mfma_f32_16x16x32_bf16(a, b, tg[p], 0,0,0);
    }
    float4 bt4 = *(const float4*)&wsf[OFF_BTF + mt*16 + quad*4];
    #pragma unroll
    for (int r=0; r<4; r++) tg[p][r] += ((const float*)&bt4)[r];
  }

  float mx = -3.0e38f;
  #pragma unroll
  for (int p=0; p<4; p++)
    #pragma unroll
    for (int r=0; r<4; r++) mx = fmaxf(mx, tg[p][r]);
  mx = fmaxf(mx, __shfl_xor(mx, 16, 64));
  mx = fmaxf(mx, __shfl_xor(mx, 32, 64));
  wred[wv][ln15] = mx;
  __syncthreads();
  float gmx = fmaxf(fmaxf(wred[0][ln15], wred[1][ln15]), fmaxf(wred[2][ln15], wred[3][ln15]));
  __syncthreads();
  float s = 0.f;
  #pragma unroll
  for (int p=0; p<4; p++)
    #pragma unroll
    for (int r=0; r<4; r++) s += __expf(tg[p][r] - gmx);
  s += __shfl_xor(s, 16, 64);
  s += __shfl_xor(s, 32, 64);
  wred[wv][ln15] = s;
  __syncthreads();
  float gs = (wred[0][ln15]+wred[1][ln15]) + (wred[2][ln15]+wred[3][ln15]);
  float lz = gmx + __logf(gs);

  if (FINAL){
    if (ln15 == 0){
      const int f32o = ((const int*)wsf)[1] != 0;
      #pragma unroll
      for (int p=0; p<4; p++){
        #pragma unroll
        for (int r=0; r<4; r++){
          int m = (wv*4+p)*16 + quad*4 + r;
          float v = tg[p][r] - lz;
          if (f32o) ((float*)dout)[m] = v;
          else      ((ushort*)dout)[m] = f2b(v);
        }
      }
    }
    return;
  }
  int onode = nt*16 + ln15;
  if (onode < nNodes){
    #pragma unroll
    for (int p=0; p<4; p++){
      int m = (wv*4+p)*16 + quad*4;
      ushort ob[4];
      #pragma unroll
      for (int r=0; r<4; r++) ob[r] = f2b(tg[p][r] - lz);
      uint2 uu;
      uu.x = (unsigned)ob[0] | ((unsigned)ob[1]<<16);
      uu.y = (unsigned)ob[2] | ((unsigned)ob[3]<<16);
      *(uint2*)&OutNext[(size_t)onode*256 + m] = uu;
    }
  }
}

extern "C" void kernel_launch(void* const* d_in, const int* in_sizes, int n_in,
                              void* d_out, int out_size, void* d_ws, size_t ws_size,
                              hipStream_t stream)
{
  (void)in_sizes; (void)n_in; (void)out_size; (void)ws_size;
  const int* idents = (const int*)d_in[0];
  const void* emb   = d_in[1];
  const void* W_ih  = d_in[2];
  const void* W_hh  = d_in[3];
  const void* b_ih  = d_in[4];
  const void* b_hh  = d_in[5];
  const void* Wc    = d_in[6];
  const void* bc    = d_in[7];
  const void* Wt    = d_in[8];
  const void* bt    = d_in[9];
  const void* linit = d_in[10];

  float* wsf = (float*)d_ws;
  ushort* slabA = (ushort*)(wsf + OFF_SLABS);
  ushort* slabB = slabA + (size_t)16384*256;
  ushort* Hb0   = slabB + (size_t)4096*256;
  ushort* Hb1   = Hb0 + (size_t)1024*256;
  float*  Cb    = (float*)(Hb1 + (size_t)1024*256);

  init_kernel  <<<1, 64, 0, stream>>>((int*)d_ws);
  detect_kernel<<<16, 256, 0, stream>>>((int*)d_ws, (const uint4*)W_ih);
  z1_kernel    <<<4, 256, 0, stream>>>(wsf, W_ih, b_ih, b_hh, bt, linit);
  prep_kernel  <<<512, 256, 0, stream>>>(wsf, W_ih, W_hh, Wc, Wt);
  ewc_kernel   <<<NVOCAB, 256, 0, stream>>>(wsf, Wc, bc, emb);
  h1_kernel    <<<1, 256, 0, stream>>>(wsf);
  hh1_kernel   <<<5, 256, 0, stream>>>(wsf, W_hh, Wc);
  tag8_kernel  <<<2, 256, 0, stream>>>(wsf);
  p8_kernel    <<<32, 64, 0, stream>>>(wsf);

  // big levels fused
  level_kernel<2,true ><<<512,1024,0,stream>>>(wsf, nullptr, idents, 5461, 21845, 16384, 65536, slabA);
  level_kernel<2,false><<<128,1024,0,stream>>>(wsf, slabA,   idents, 1365, 0,     4096,  0,     slabB);

  // small levels: M-parallel stepped path (4 steps + fin per level)
  struct Lv { int n, offL; ushort *P, *O; };
  const Lv lv[6] = {
    {1024, 341, slabB, slabA},
    { 256,  85, slabA, slabB},
    {  64,  21, slabB, slabA},
    {  16,   5, slabA, slabB},
    {   4,   1, slabB, slabA},
    {   1,   0, slabA, nullptr},
  };
  for (int i=0; i<6; i++){
    int nt = (lv[i].n + 15) / 16;
    dim3 gs(nt*16);
    step_kernel<true ><<<gs, 64, 0, stream>>>(wsf, lv[i].P, nullptr, Hb1, Cb, lv[i].n, 0);
    step_kernel<false><<<gs, 64, 0, stream>>>(wsf, lv[i].P, Hb1, Hb0, Cb, lv[i].n, 1);
    step_kernel<false><<<gs, 64, 0, stream>>>(wsf, lv[i].P, Hb0, Hb1, Cb, lv[i].n, 2);
    step_kernel<false><<<gs, 64, 0, stream>>>(wsf, lv[i].P, Hb1, Hb0, Cb, lv[i].n, 3);
    if (i < 5) fin_kernel<false><<<nt, 256, 0, stream>>>(wsf, Hb0, idents, lv[i].offL, lv[i].n, lv[i].O, nullptr);
    else       fin_kernel<true ><<<1,  256, 0, stream>>>(wsf, Hb0, idents, 0, 1, nullptr, d_out);
  }
}

// Round 10
// 547.373 us; speedup vs baseline: 1.1039x; 1.1039x over previous
//
#include <hip/hip_runtime.h>
#include <hip/hip_bf16.h>
#include <cstdint>
#include <cstddef>

typedef __hip_bfloat16 bf16;
typedef unsigned short ushort;
typedef __attribute__((ext_vector_type(8))) short bf16x8;
typedef __attribute__((ext_vector_type(4))) float f32x4;

#define HDIM 256
#define NVOCAB 26
#define STR 264

// ---- workspace layout (float offsets) ----
#define OFF_BSUM  16
#define OFF_Z1    (OFF_BSUM+1024)
#define OFF_HH1   (OFF_Z1+1024)
#define OFF_H1    (OFF_HH1+1024)
#define OFF_C1    (OFF_H1+256)
#define OFF_WCH1  (OFF_C1+256)
#define OFF_BTF   (OFF_WCH1+256)
#define OFF_EWC   (OFF_BTF+256)          // [26][256] f32
#define OFF_P8    (OFF_EWC+6656)         // [26][1024] f32
#define OFF_SCB   (OFF_P8+26624)         // [32][256] ushort (scomb bf16 rows)
#define OFF_O8B   (OFF_SCB+4096)         // [32][256] ushort (out8 bf16 rows)
#define OFF_FRAG  (OFF_O8B+4096)         // ushort frag tables
#define OFF_SLABS (OFF_FRAG+327680)

__device__ __forceinline__ float sigmf(float x){ return 1.0f/(1.0f+__expf(-x)); }
__device__ __forceinline__ float tanhfast(float x){ return 1.0f - 2.0f/(__expf(2.0f*x)+1.0f); }
__device__ __forceinline__ ushort f2b(float x){ bf16 h = __float2bfloat16(x); return *(ushort*)&h; }
__device__ __forceinline__ float ldin(const void* p, int i, int f32){
  if (f32) return ((const float*)p)[i];
  unsigned int w = ((unsigned int)((const ushort*)p)[i]) << 16;
  return __uint_as_float(w);
}
__device__ __forceinline__ void ld8(const void* p, int i, int f32, float* o){
  if (f32){
    float4 a = *(const float4*)((const float*)p + i);
    float4 b = *(const float4*)((const float*)p + i + 4);
    o[0]=a.x;o[1]=a.y;o[2]=a.z;o[3]=a.w;o[4]=b.x;o[5]=b.y;o[6]=b.z;o[7]=b.w;
  } else {
    uint4 u = *(const uint4*)((const ushort*)p + i);
    unsigned w0=u.x,w1=u.y,w2=u.z,w3=u.w;
    o[0]=__uint_as_float(w0<<16); o[1]=__uint_as_float(w0&0xFFFF0000u);
    o[2]=__uint_as_float(w1<<16); o[3]=__uint_as_float(w1&0xFFFF0000u);
    o[4]=__uint_as_float(w2<<16); o[5]=__uint_as_float(w2&0xFFFF0000u);
    o[6]=__uint_as_float(w3<<16); o[7]=__uint_as_float(w3&0xFFFF0000u);
  }
}

__global__ void init_kernel(int* wsI){ if (threadIdx.x<4) wsI[threadIdx.x]=0; }

__global__ __launch_bounds__(256) void detect_kernel(int* wsI, const uint4* wih4){
  int c=0;
  for (int i = blockIdx.x*blockDim.x + threadIdx.x; i < 32768; i += gridDim.x*blockDim.x){
    uint4 u = wih4[i];
    unsigned w[4] = {u.x,u.y,u.z,u.w};
    #pragma unroll
    for (int j=0;j<4;j++){
      if ((w[j] & 0x7F80u) == 0x7F80u) c++;
      if ((w[j] & 0x7F800000u) == 0x7F800000u) c++;
    }
  }
  #pragma unroll
  for (int o=32;o>0;o>>=1) c += __shfl_xor(c,o,64);
  if ((threadIdx.x&63)==0 && c) atomicAdd(&wsI[1], c);
}

__global__ __launch_bounds__(256) void z1_kernel(
    float* __restrict__ wsf, const void* W_ih, const void* b_ih, const void* b_hh,
    const void* bt, const void* linit)
{
  const int f32 = ((const int*)wsf)[1] != 0;
  __shared__ float sx[256];
  int tid = threadIdx.x;
  int r = blockIdx.x*256 + tid;
  sx[tid] = ldin(linit, tid, f32);
  __syncthreads();
  float a = ldin(b_ih, r, f32) + ldin(b_hh, r, f32);
  wsf[OFF_BSUM + r] = a;
  float z = a;
  #pragma unroll 8
  for (int k=0;k<256;k+=8){
    float w[8]; ld8(W_ih, r*256+k, f32, w);
    #pragma unroll
    for (int j=0;j<8;j++) z += w[j]*sx[k+j];
  }
  wsf[OFF_Z1 + r] = z;
  if (blockIdx.x==0) wsf[OFF_BTF + tid] = ldin(bt, tid, f32);
}

__global__ __launch_bounds__(256) void h1_kernel(float* __restrict__ wsf){
  int e = threadIdx.x;
  float zi = wsf[OFF_Z1+e], zg = wsf[OFF_Z1+512+e], zo = wsf[OFF_Z1+768+e];
  float c1 = sigmf(zi)*tanhfast(zg);
  float h1 = sigmf(zo)*tanhfast(c1);
  wsf[OFF_H1+e]=h1; wsf[OFF_C1+e]=c1;
}

// blocks 0..3: hh1 rows; block 4: wch1 + scomb bf16 rows (needs EWC done)
__global__ __launch_bounds__(256) void hh1_kernel(float* __restrict__ wsf, const void* W_hh, const void* Wc){
  const int f32 = ((const int*)wsf)[1] != 0;
  __shared__ float sh1[256];
  int tid = threadIdx.x;
  sh1[tid] = wsf[OFF_H1+tid];
  __syncthreads();
  if (blockIdx.x < 4){
    int r = blockIdx.x*256 + tid;
    float z = wsf[OFF_BSUM + r];
    #pragma unroll 8
    for (int k=0;k<256;k+=8){
      float w[8]; ld8(W_hh, r*256+k, f32, w);
      #pragma unroll
      for (int j=0;j<8;j++) z += w[j]*sh1[k+j];
    }
    wsf[OFF_HH1 + r] = z;
  } else {
    float a = 0.f;
    #pragma unroll 8
    for (int k=0;k<256;k+=8){
      float w[8]; ld8(Wc, tid*512+k, f32, w);
      #pragma unroll
      for (int j=0;j<8;j++) a += w[j]*sh1[k+j];
    }
    wsf[OFF_WCH1 + tid] = a;
    ushort* SCB = (ushort*)(wsf + OFF_SCB);
    #pragma unroll 1
    for (int v32=0; v32<32; v32++){
      int v = v32 < NVOCAB ? v32 : NVOCAB-1;
      SCB[v32*256 + tid] = f2b(a + wsf[OFF_EWC + v*256 + tid]);
    }
  }
}

__global__ __launch_bounds__(256) void ewc_kernel(
    float* __restrict__ wsf, const void* Wc, const void* bc, const void* emb)
{
  const int f32 = ((const int*)wsf)[1] != 0;
  int v = blockIdx.x, i = threadIdx.x;
  __shared__ float se[256];
  se[i] = ldin(emb, v*256+i, f32);
  __syncthreads();
  float a = ldin(bc, i, f32);
  #pragma unroll 8
  for (int k=0;k<256;k+=8){
    float w[8]; ld8(Wc, i*512+256+k, f32, w);
    #pragma unroll
    for (int j=0;j<8;j++) a += w[j]*se[k+j];
  }
  wsf[OFF_EWC + v*256 + i] = a;
}

// A-fragment tables: chunk=(mt*8+ks), lane L, j: m=mt*16+(L&15), k=ks*32+(L>>4)*8+j
__global__ __launch_bounds__(256) void prep_kernel(
    float* __restrict__ wsf, const void* W_ih, const void* W_hh, const void* Wc, const void* Wt)
{
  const int f32 = ((const int*)wsf)[1] != 0;
  ushort* FWIH = (ushort*)(wsf + OFF_FRAG);
  ushort* FWHH = FWIH + 262144;
  ushort* FWC1 = FWHH + 262144;
  ushort* FWT  = FWC1 + 65536;
  int stride = gridDim.x*blockDim.x;
  int t0 = blockIdx.x*blockDim.x + threadIdx.x;
  for (int idx=t0; idx<262144; idx+=stride){
    int c = idx>>9, r = idx&511, L = r>>3, j = r&7;
    int mt = c>>3, ks = c&7;
    int m = (mt<<4) | (L&15);
    int k = (ks<<5) + ((L>>4)<<3) + j;
    FWIH[idx] = f2b(ldin(W_ih, m*256+k, f32));
    FWHH[idx] = f2b(ldin(W_hh, m*256+k, f32));
  }
  for (int idx=t0; idx<65536; idx+=stride){
    int c = idx>>9, r = idx&511, L = r>>3, j = r&7;
    int mt = c>>3, ks = c&7;
    int m = (mt<<4) | (L&15);
    int k = (ks<<5) + ((L>>4)<<3) + j;
    FWC1[idx] = f2b(ldin(Wc, m*512+k, f32));
    FWT [idx] = f2b(ldin(Wt, m*256+k, f32));
  }
}

// ---- tag8: tag = Wt@scomb + bt, log-softmax, out8 bf16 rows (26 vocab) ----
__global__ __launch_bounds__(256) void tag8_kernel(float* __restrict__ wsf){
  __shared__ float wred[4][16];
  const int tid=threadIdx.x, wv=tid>>6, lane=tid&63, ln15=lane&15, quad=lane>>4;
  const int nt = blockIdx.x;
  const ushort* FWT = (const ushort*)(wsf + OFF_FRAG) + 262144 + 262144 + 65536;
  const ushort* SCB = (const ushort*)(wsf + OFF_SCB);
  ushort* O8B = (ushort*)(wsf + OFF_O8B);
  const int row = nt*16 + ln15;

  f32x4 tg[4];
  #pragma unroll 1
  for (int p=0; p<4; p++){
    const int mt = wv*4 + p;
    tg[p] = (f32x4){0.f,0.f,0.f,0.f};
    #pragma unroll
    for (int ks=0; ks<8; ks++){
      bf16x8 a = *(const bf16x8*)&FWT[((mt*8+ks)<<9) + (lane<<3)];
      bf16x8 b = *(const bf16x8*)&SCB[row*256 + ks*32 + quad*8];
      tg[p] = __builtin_amdgcn_mfma_f32_16x16x32_bf16(a, b, tg[p], 0,0,0);
    }
    float4 bt4 = *(const float4*)&wsf[OFF_BTF + mt*16 + quad*4];
    #pragma unroll
    for (int r=0; r<4; r++) tg[p][r] += ((const float*)&bt4)[r];
  }

  float mx = -3.0e38f;
  #pragma unroll
  for (int p=0; p<4; p++)
    #pragma unroll
    for (int r=0; r<4; r++) mx = fmaxf(mx, tg[p][r]);
  mx = fmaxf(mx, __shfl_xor(mx, 16, 64));
  mx = fmaxf(mx, __shfl_xor(mx, 32, 64));
  wred[wv][ln15] = mx;
  __syncthreads();
  float gmx = fmaxf(fmaxf(wred[0][ln15], wred[1][ln15]), fmaxf(wred[2][ln15], wred[3][ln15]));
  __syncthreads();
  float s = 0.f;
  #pragma unroll
  for (int p=0; p<4; p++)
    #pragma unroll
    for (int r=0; r<4; r++) s += __expf(tg[p][r] - gmx);
  s += __shfl_xor(s, 16, 64);
  s += __shfl_xor(s, 32, 64);
  wred[wv][ln15] = s;
  __syncthreads();
  float gs = (wred[0][ln15]+wred[1][ln15]) + (wred[2][ln15]+wred[3][ln15]);
  float lz = gmx + __logf(gs);

  #pragma unroll
  for (int p=0; p<4; p++){
    int m = (wv*4+p)*16 + quad*4;
    ushort ob[4];
    #pragma unroll
    for (int r=0; r<4; r++) ob[r] = f2b(tg[p][r] - lz);
    uint2 uu;
    uu.x = (unsigned)ob[0] | ((unsigned)ob[1]<<16);
    uu.y = (unsigned)ob[2] | ((unsigned)ob[3]<<16);
    *(uint2*)&O8B[row*256 + m] = uu;
  }
}

// ---- p8: P8[v] = W_ih @ out8[v] via MFMA; grid = 2x16 blocks of 64 ----
__global__ __launch_bounds__(64) void p8_kernel(float* __restrict__ wsf){
  const int nt = blockIdx.x >> 4, eb = blockIdx.x & 15;
  const int lane = threadIdx.x, ln15 = lane & 15, quad = lane >> 4;
  const ushort* FWIH = (const ushort*)(wsf + OFF_FRAG);
  const ushort* O8B  = (const ushort*)(wsf + OFF_O8B);
  const int row = nt*16 + ln15;

  f32x4 acc[4];
  #pragma unroll
  for (int g=0; g<4; g++) acc[g] = (f32x4){0.f,0.f,0.f,0.f};
  #pragma unroll
  for (int ks=0; ks<8; ks++){
    bf16x8 b = *(const bf16x8*)&O8B[row*256 + ks*32 + quad*8];
    #pragma unroll
    for (int g=0; g<4; g++){
      int mt = g*16 + eb;
      bf16x8 a = *(const bf16x8*)&FWIH[((mt*8+ks)<<9) + (lane<<3)];
      acc[g] = __builtin_amdgcn_mfma_f32_16x16x32_bf16(a, b, acc[g], 0,0,0);
    }
  }
  if (row < NVOCAB){
    #pragma unroll
    for (int g=0; g<4; g++)
      *(float4*)&wsf[OFF_P8 + row*1024 + g*256 + eb*16 + quad*4] =
        (float4){acc[g][0], acc[g][1], acc[g][2], acc[g][3]};
  }
}

// ---- fused level kernel for big levels (7,6): 16 nodes/block, 16 waves ----
// NT=1 keeps the live set ~50 VGPRs: the B=1024 allocator caps at 64 VGPR
// (both launch_bounds(,4) and waves_per_eu(4,4) failed to lift it — r8/r9),
// so the fix is fitting under 64, not fighting for 128.
template<int NT, bool GATHER>
__global__ __launch_bounds__(1024) void level_kernel(
    const float* __restrict__ wsf, const ushort* __restrict__ OutPrev,
    const int* __restrict__ idents, int offL, int offC, int nNodes, int nChild,
    ushort* __restrict__ OutNext)
{
  constexpr int NN = NT*16;
  __shared__ __align__(16) ushort Hlds[2][NN*STR];
  __shared__ __align__(16) ushort Xlds[GATHER ? 16 : NN*STR];
  __shared__ float wred[16][NN];
  __shared__ int sid[NN];
  __shared__ int sid4[GATHER ? NN*4 : 4];

  const int tid  = threadIdx.x;
  const int wv   = tid >> 6;
  const int lane = tid & 63;
  const int ln15 = lane & 15;
  const int quad = lane >> 4;
  const int j0   = blockIdx.x * NN;

  const ushort* FWIH = (const ushort*)(wsf + OFF_FRAG);
  const ushort* FWHH = FWIH + 262144;
  const ushort* FWC1 = FWHH + 262144;
  const ushort* FWT  = FWC1 + 65536;
  const float*  P8   = wsf + OFF_P8;
  const float*  EWcP = wsf + OFF_EWC;

  if (tid<NN){ int nd=j0+tid; if (nd>=nNodes) nd=nNodes-1; sid[tid]=idents[offL+nd]; }
  if (GATHER){
    for (int i=tid; i<NN*4; i+=1024){
      int ci = j0*4 + i; if (ci >= nChild) ci = nChild-1;
      sid4[i] = idents[offC + ci];
    }
  }

  f32x4 creg[NT];

  #pragma unroll 1
  for (int t=1; t<=4; t++){
    if (!GATHER){
      for (int i=tid; i<NN*32; i+=1024){
        int n = i>>5, off = i&31;
        int node = j0+n; if (node>=nNodes) node=nNodes-1;
        uint4 v = ((const uint4*)OutPrev)[((size_t)node*4 + (t-1))*32 + off];
        *(uint4*)&Xlds[n*STR + off*8] = v;
      }
    }
    __syncthreads();
    const int rb = (t-1)&1, wb = t&1;

    f32x4 acc[4][NT];
    #pragma unroll
    for (int g=0; g<4; g++)
      #pragma unroll
      for (int n=0; n<NT; n++) acc[g][n] = (f32x4){0.f,0.f,0.f,0.f};

    if (t>=2){
      #pragma unroll
      for (int ks=0; ks<8; ks++){
        bf16x8 bh[NT];
        #pragma unroll
        for (int n=0; n<NT; n++)
          bh[n] = *(const bf16x8*)&Hlds[rb][(n*16+ln15)*STR + ks*32 + quad*8];
        #pragma unroll
        for (int g=0; g<4; g++){
          int mt = g*16 + wv;
          bf16x8 a = *(const bf16x8*)&FWHH[((mt*8+ks)<<9) + (lane<<3)];
          #pragma unroll
          for (int n=0; n<NT; n++)
            acc[g][n] = __builtin_amdgcn_mfma_f32_16x16x32_bf16(a, bh[n], acc[g][n], 0,0,0);
        }
      }
    }
    if (!GATHER){
      #pragma unroll
      for (int ks=0; ks<8; ks++){
        bf16x8 bx[NT];
        #pragma unroll
        for (int n=0; n<NT; n++)
          bx[n] = *(const bf16x8*)&Xlds[(n*16+ln15)*STR + ks*32 + quad*8];
        #pragma unroll
        for (int g=0; g<4; g++){
          int mt = g*16 + wv;
          bf16x8 a = *(const bf16x8*)&FWIH[((mt*8+ks)<<9) + (lane<<3)];
          #pragma unroll
          for (int n=0; n<NT; n++)
            acc[g][n] = __builtin_amdgcn_mfma_f32_16x16x32_bf16(a, bx[n], acc[g][n], 0,0,0);
        }
      }
    }

    // fold base bias into acc (one float4 live at a time)
    const float* baseP = wsf + ((t==1) ? OFF_HH1 : OFF_BSUM);
    const int eb = wv*16;
    #pragma unroll
    for (int g=0; g<4; g++){
      float4 bg = *(const float4*)&baseP[g*256 + eb + quad*4];
      #pragma unroll
      for (int n=0; n<NT; n++){
        acc[g][n][0]+=bg.x; acc[g][n][1]+=bg.y; acc[g][n][2]+=bg.z; acc[g][n][3]+=bg.w;
      }
    }
    // fold gather input into acc
    if (GATHER){
      #pragma unroll
      for (int n=0; n<NT; n++){
        const float* pg = P8 + (size_t)sid4[(n*16+ln15)*4 + (t-1)]*1024;
        #pragma unroll
        for (int g=0; g<4; g++){
          float4 xg = *(const float4*)&pg[g*256 + eb + quad*4];
          acc[g][n][0]+=xg.x; acc[g][n][1]+=xg.y; acc[g][n][2]+=xg.z; acc[g][n][3]+=xg.w;
        }
      }
    }
    // gate math
    #pragma unroll
    for (int n=0; n<NT; n++){
      f32x4 cp;
      if (t==1){
        float4 cc = *(const float4*)&wsf[OFF_C1 + eb + quad*4];
        cp = (f32x4){cc.x,cc.y,cc.z,cc.w};
      } else cp = creg[n];
      ushort hb[4];
      #pragma unroll
      for (int r=0; r<4; r++){
        float cn = sigmf(acc[1][n][r])*cp[r] + sigmf(acc[0][n][r])*tanhfast(acc[2][n][r]);
        creg[n][r] = cn;
        hb[r] = f2b(sigmf(acc[3][n][r])*tanhfast(cn));
      }
      uint2 uu;
      uu.x = (unsigned)hb[0] | ((unsigned)hb[1]<<16);
      uu.y = (unsigned)hb[2] | ((unsigned)hb[3]<<16);
      *(uint2*)&Hlds[wb][(n*16+ln15)*STR + eb + quad*4] = uu;
    }
    __syncthreads();
  }

  // combined = Wc1@h + EWc[id]
  {
    f32x4 ac[NT];
    #pragma unroll
    for (int n=0; n<NT; n++) ac[n] = (f32x4){0.f,0.f,0.f,0.f};
    #pragma unroll
    for (int ks=0; ks<8; ks++){
      bf16x8 a = *(const bf16x8*)&FWC1[((wv*8+ks)<<9) + (lane<<3)];
      #pragma unroll
      for (int n=0; n<NT; n++){
        bf16x8 b = *(const bf16x8*)&Hlds[0][(n*16+ln15)*STR + ks*32 + quad*8];
        ac[n] = __builtin_amdgcn_mfma_f32_16x16x32_bf16(a, b, ac[n], 0,0,0);
      }
    }
    #pragma unroll
    for (int n=0; n<NT; n++){
      float4 ew = *(const float4*)&EWcP[(size_t)sid[n*16+ln15]*256 + wv*16 + quad*4];
      ushort cb[4];
      #pragma unroll
      for (int r=0; r<4; r++) cb[r] = f2b(ac[n][r] + ((const float*)&ew)[r]);
      uint2 uu;
      uu.x = (unsigned)cb[0] | ((unsigned)cb[1]<<16);
      uu.y = (unsigned)cb[2] | ((unsigned)cb[3]<<16);
      *(uint2*)&Hlds[1][(n*16+ln15)*STR + wv*16 + quad*4] = uu;
    }
  }
  __syncthreads();

  // tag = Wt@combined + bt
  f32x4 tg[NT];
  {
    #pragma unroll
    for (int n=0; n<NT; n++) tg[n] = (f32x4){0.f,0.f,0.f,0.f};
    #pragma unroll
    for (int ks=0; ks<8; ks++){
      bf16x8 a = *(const bf16x8*)&FWT[((wv*8+ks)<<9) + (lane<<3)];
      #pragma unroll
      for (int n=0; n<NT; n++){
        bf16x8 b = *(const bf16x8*)&Hlds[1][(n*16+ln15)*STR + ks*32 + quad*8];
        tg[n] = __builtin_amdgcn_mfma_f32_16x16x32_bf16(a, b, tg[n], 0,0,0);
      }
    }
    float4 bt4 = *(const float4*)&wsf[OFF_BTF + wv*16 + quad*4];
    #pragma unroll
    for (int n=0; n<NT; n++)
      #pragma unroll
      for (int r=0; r<4; r++) tg[n][r] += ((const float*)&bt4)[r];
  }

  float gmx[NT], gs[NT];
  {
    #pragma unroll
    for (int n=0; n<NT; n++){
      float mx = fmaxf(fmaxf(tg[n][0],tg[n][1]), fmaxf(tg[n][2],tg[n][3]));
      mx = fmaxf(mx, __shfl_xor(mx, 16, 64));
      mx = fmaxf(mx, __shfl_xor(mx, 32, 64));
      wred[wv][n*16+ln15] = mx;
    }
    __syncthreads();
    #pragma unroll
    for (int n=0; n<NT; n++){
      float m = wred[0][n*16+ln15];
      #pragma unroll
      for (int w=1; w<16; w++) m = fmaxf(m, wred[w][n*16+ln15]);
      gmx[n] = m;
    }
    __syncthreads();
    #pragma unroll
    for (int n=0; n<NT; n++){
      float s = __expf(tg[n][0]-gmx[n]) + __expf(tg[n][1]-gmx[n])
              + __expf(tg[n][2]-gmx[n]) + __expf(tg[n][3]-gmx[n]);
      s += __shfl_xor(s, 16, 64);
      s += __shfl_xor(s, 32, 64);
      wred[wv][n*16+ln15] = s;
    }
    __syncthreads();
    #pragma unroll
    for (int n=0; n<NT; n++){
      float s = 0.f;
      #pragma unroll
      for (int w=0; w<16; w++) s += wred[w][n*16+ln15];
      gs[n] = s;
    }
  }

  #pragma unroll
  for (int n=0; n<NT; n++){
    int node = j0 + n*16 + ln15;
    if (node >= nNodes) continue;
    float lz = gmx[n] + __logf(gs[n]);
    ushort ob[4];
    #pragma unroll
    for (int r=0; r<4; r++) ob[r] = f2b(tg[n][r] - lz);
    uint2 uu;
    uu.x = (unsigned)ob[0] | ((unsigned)ob[1]<<16);
    uu.y = (unsigned)ob[2] | ((unsigned)ob[3]<<16);
    *(uint2*)&OutNext[(size_t)node*256 + wv*16 + quad*4] = uu;
  }
}

// ---- one LSTM t-step for small levels: M-parallel across the grid ----
template<bool FIRST>
__global__ __launch_bounds__(64) void step_kernel(
    const float* __restrict__ wsf, const ushort* __restrict__ OutPrev,
    const ushort* __restrict__ Hin, ushort* __restrict__ Hout,
    float* __restrict__ Cbuf, int nNodes, int tm1)
{
  const int nt   = blockIdx.x >> 4;
  const int eb   = blockIdx.x & 15;
  const int lane = threadIdx.x;
  const int ln15 = lane & 15;
  const int quad = lane >> 4;

  const ushort* FWIH = (const ushort*)(wsf + OFF_FRAG);
  const ushort* FWHH = FWIH + 262144;

  int node = nt*16 + ln15; if (node >= nNodes) node = nNodes-1;
  const int rowX = (node*4 + tm1) * 256;
  const int rowH = node * 256;

  f32x4 acc[4];
  #pragma unroll
  for (int g=0; g<4; g++) acc[g] = (f32x4){0.f,0.f,0.f,0.f};

  #pragma unroll
  for (int ks=0; ks<8; ks++){
    bf16x8 bx = *(const bf16x8*)&OutPrev[rowX + ks*32 + quad*8];
    bf16x8 bh;
    if (!FIRST) bh = *(const bf16x8*)&Hin[rowH + ks*32 + quad*8];
    #pragma unroll
    for (int g=0; g<4; g++){
      int mt = g*16 + eb;
      bf16x8 a = *(const bf16x8*)&FWIH[((mt*8+ks)<<9) + (lane<<3)];
      acc[g] = __builtin_amdgcn_mfma_f32_16x16x32_bf16(a, bx, acc[g], 0,0,0);
      if (!FIRST){
        bf16x8 a2 = *(const bf16x8*)&FWHH[((mt*8+ks)<<9) + (lane<<3)];
        acc[g] = __builtin_amdgcn_mfma_f32_16x16x32_bf16(a2, bh, acc[g], 0,0,0);
      }
    }
  }

  const float* baseP = wsf + (FIRST ? OFF_HH1 : OFF_BSUM);
  const int e0 = eb*16 + quad*4;
  float4 b0 = *(const float4*)&baseP[       e0];
  float4 b1 = *(const float4*)&baseP[ 256 + e0];
  float4 b2 = *(const float4*)&baseP[ 512 + e0];
  float4 b3 = *(const float4*)&baseP[ 768 + e0];
  float4 cp;
  if (FIRST) cp = *(const float4*)&wsf[OFF_C1 + e0];
  else       cp = *(const float4*)&Cbuf[rowH + e0];

  float cn4[4]; ushort hb[4];
  #pragma unroll
  for (int r=0; r<4; r++){
    float zi = acc[0][r] + ((const float*)&b0)[r];
    float zf = acc[1][r] + ((const float*)&b1)[r];
    float zg = acc[2][r] + ((const float*)&b2)[r];
    float zo = acc[3][r] + ((const float*)&b3)[r];
    float cn = sigmf(zf)*((const float*)&cp)[r] + sigmf(zi)*tanhfast(zg);
    cn4[r] = cn;
    hb[r] = f2b(sigmf(zo)*tanhfast(cn));
  }
  *(float4*)&Cbuf[rowH + e0] = (float4){cn4[0],cn4[1],cn4[2],cn4[3]};
  uint2 uu;
  uu.x = (unsigned)hb[0] | ((unsigned)hb[1]<<16);
  uu.y = (unsigned)hb[2] | ((unsigned)hb[3]<<16);
  *(uint2*)&Hout[rowH + e0] = uu;
}

// ---- epilogue for small levels: combine -> tag -> log-softmax -> out ----
template<bool FINAL>
__global__ __launch_bounds__(256) void fin_kernel(
    const float* __restrict__ wsf, const ushort* __restrict__ Hfin,
    const int* __restrict__ idents, int offL, int nNodes,
    ushort* __restrict__ OutNext, void* __restrict__ dout)
{
  __shared__ __align__(16) ushort Clds[16*STR];
  __shared__ float wred[4][16];
  const int tid  = threadIdx.x;
  const int wv   = tid >> 6;
  const int lane = tid & 63;
  const int ln15 = lane & 15;
  const int quad = lane >> 4;
  const int nt   = blockIdx.x;

  const ushort* FWIH = (const ushort*)(wsf + OFF_FRAG);
  const ushort* FWC1 = FWIH + 262144 + 262144;
  const ushort* FWT  = FWC1 + 65536;
  const float*  EWcP = wsf + OFF_EWC;

  int node = nt*16 + ln15; if (node >= nNodes) node = nNodes-1;
  const int myid = idents[offL + node];
  const int rowH = node * 256;

  #pragma unroll 1
  for (int p=0; p<4; p++){
    const int mt = wv*4 + p;
    f32x4 ac = (f32x4){0.f,0.f,0.f,0.f};
    #pragma unroll
    for (int ks=0; ks<8; ks++){
      bf16x8 a = *(const bf16x8*)&FWC1[((mt*8+ks)<<9) + (lane<<3)];
      bf16x8 b = *(const bf16x8*)&Hfin[rowH + ks*32 + quad*8];
      ac = __builtin_amdgcn_mfma_f32_16x16x32_bf16(a, b, ac, 0,0,0);
    }
    float4 ew = *(const float4*)&EWcP[(size_t)myid*256 + mt*16 + quad*4];
    ushort cb[4];
    #pragma unroll
    for (int r=0; r<4; r++) cb[r] = f2b(ac[r] + ((const float*)&ew)[r]);
    uint2 uu;
    uu.x = (unsigned)cb[0] | ((unsigned)cb[1]<<16);
    uu.y = (unsigned)cb[2] | ((unsigned)cb[3]<<16);
    *(uint2*)&Clds[ln15*STR + mt*16 + quad*4] = uu;
  }
  __syncthreads();

  f32x4 tg[4];
  #pragma unroll 1
  for (int p=0; p<4; p++){
    const int mt = wv*4 + p;
    tg[p] = (f32x4){0.f,0.f,0.f,0.f};
    #pragma unroll
    for (int ks=0; ks<8; ks++){
      bf16x8 a = *(const bf16x8*)&FWT[((mt*8+ks)<<9) + (lane<<3)];
      bf16x8 b = *(const bf16x8*)&Clds[ln15*STR + ks*32 + quad*8];
      tg[p] = __builtin_amdgcn_mfma_f32_16x16x32_bf16(a, b, tg[p], 0,0,0);
    }
    float4 bt4 = *(const float4*)&wsf[OFF_BTF + mt*16 + quad*4];
    #pragma unroll
    for (int r=0; r<4; r++) tg[p][r] += ((const float*)&bt4)[r];
  }

  float mx = -3.0e38f;
  #pragma unroll
  for (int p=0; p<4; p++)
    #pragma unroll
    for (int r=0; r<4; r++) mx = fmaxf(mx, tg[p][r]);
  mx = fmaxf(mx, __shfl_xor(mx, 16, 64));
  mx = fmaxf(mx, __shfl_xor(mx, 32, 64));
  wred[wv][ln15] = mx;
  __syncthreads();
  float gmx = fmaxf(fmaxf(wred[0][ln15], wred[1][ln15]), fmaxf(wred[2][ln15], wred[3][ln15]));
  __syncthreads();
  float s = 0.f;
  #pragma unroll
  for (int p=0; p<4; p++)
    #pragma unroll
    for (int r=0; r<4; r++) s += __expf(tg[p][r] - gmx);
  s += __shfl_xor(s, 16, 64);
  s += __shfl_xor(s, 32, 64);
  wred[wv][ln15] = s;
  __syncthreads();
  float gs = (wred[0][ln15]+wred[1][ln15]) + (wred[2][ln15]+wred[3][ln15]);
  float lz = gmx + __logf(gs);

  if (FINAL){
    if (ln15 == 0){
      const int f32o = ((const int*)wsf)[1] != 0;
      #pragma unroll
      for (int p=0; p<4; p++){
        #pragma unroll
        for (int r=0; r<4; r++){
          int m = (wv*4+p)*16 + quad*4 + r;
          float v = tg[p][r] - lz;
          if (f32o) ((float*)dout)[m] = v;
          else      ((ushort*)dout)[m] = f2b(v);
        }
      }
    }
    return;
  }
  int onode = nt*16 + ln15;
  if (onode < nNodes){
    #pragma unroll
    for (int p=0; p<4; p++){
      int m = (wv*4+p)*16 + quad*4;
      ushort ob[4];
      #pragma unroll
      for (int r=0; r<4; r++) ob[r] = f2b(tg[p][r] - lz);
      uint2 uu;
      uu.x = (unsigned)ob[0] | ((unsigned)ob[1]<<16);
      uu.y = (unsigned)ob[2] | ((unsigned)ob[3]<<16);
      *(uint2*)&OutNext[(size_t)onode*256 + m] = uu;
    }
  }
}

extern "C" void kernel_launch(void* const* d_in, const int* in_sizes, int n_in,
                              void* d_out, int out_size, void* d_ws, size_t ws_size,
                              hipStream_t stream)
{
  (void)in_sizes; (void)n_in; (void)out_size; (void)ws_size;
  const int* idents = (const int*)d_in[0];
  const void* emb   = d_in[1];
  const void* W_ih  = d_in[2];
  const void* W_hh  = d_in[3];
  const void* b_ih  = d_in[4];
  const void* b_hh  = d_in[5];
  const void* Wc    = d_in[6];
  const void* bc    = d_in[7];
  const void* Wt    = d_in[8];
  const void* bt    = d_in[9];
  const void* linit = d_in[10];

  float* wsf = (float*)d_ws;
  ushort* slabA = (ushort*)(wsf + OFF_SLABS);
  ushort* slabB = slabA + (size_t)16384*256;
  ushort* Hb0   = slabB + (size_t)4096*256;
  ushort* Hb1   = Hb0 + (size_t)1024*256;
  float*  Cb    = (float*)(Hb1 + (size_t)1024*256);

  init_kernel  <<<1, 64, 0, stream>>>((int*)d_ws);
  detect_kernel<<<16, 256, 0, stream>>>((int*)d_ws, (const uint4*)W_ih);
  z1_kernel    <<<4, 256, 0, stream>>>(wsf, W_ih, b_ih, b_hh, bt, linit);
  prep_kernel  <<<512, 256, 0, stream>>>(wsf, W_ih, W_hh, Wc, Wt);
  ewc_kernel   <<<NVOCAB, 256, 0, stream>>>(wsf, Wc, bc, emb);
  h1_kernel    <<<1, 256, 0, stream>>>(wsf);
  hh1_kernel   <<<5, 256, 0, stream>>>(wsf, W_hh, Wc);
  tag8_kernel  <<<2, 256, 0, stream>>>(wsf);
  p8_kernel    <<<32, 64, 0, stream>>>(wsf);

  // big levels fused (NT=1: 16 nodes/block)
  level_kernel<1,true ><<<1024,1024,0,stream>>>(wsf, nullptr, idents, 5461, 21845, 16384, 65536, slabA);
  level_kernel<1,false><<<256 ,1024,0,stream>>>(wsf, slabA,   idents, 1365, 0,     4096,  0,     slabB);

  // small levels: M-parallel stepped path (4 steps + fin per level)
  struct Lv { int n, offL; ushort *P, *O; };
  const Lv lv[6] = {
    {1024, 341, slabB, slabA},
    { 256,  85, slabA, slabB},
    {  64,  21, slabB, slabA},
    {  16,   5, slabA, slabB},
    {   4,   1, slabB, slabA},
    {   1,   0, slabA, nullptr},
  };
  for (int i=0; i<6; i++){
    int nt = (lv[i].n + 15) / 16;
    dim3 gs(nt*16);
    step_kernel<true ><<<gs, 64, 0, stream>>>(wsf, lv[i].P, nullptr, Hb1, Cb, lv[i].n, 0);
    step_kernel<false><<<gs, 64, 0, stream>>>(wsf, lv[i].P, Hb1, Hb0, Cb, lv[i].n, 1);
    step_kernel<false><<<gs, 64, 0, stream>>>(wsf, lv[i].P, Hb0, Hb1, Cb, lv[i].n, 2);
    step_kernel<false><<<gs, 64, 0, stream>>>(wsf, lv[i].P, Hb1, Hb0, Cb, lv[i].n, 3);
    if (i < 5) fin_kernel<false><<<nt, 256, 0, stream>>>(wsf, Hb0, idents, lv[i].offL, lv[i].n, lv[i].O, nullptr);
    else       fin_kernel<true ><<<1,  256, 0, stream>>>(wsf, Hb0, idents, 0, 1, nullptr, d_out);
  }
}

// Round 11
// 515.959 us; speedup vs baseline: 1.1711x; 1.0609x over previous
//
#include <hip/hip_runtime.h>
#include <hip/hip_bf16.h>
#include <cstdint>
#include <cstddef>

typedef __hip_bfloat16 bf16;
typedef unsigned short ushort;
typedef __attribute__((ext_vector_type(8))) short bf16x8;
typedef __attribute__((ext_vector_type(4))) float f32x4;

#define HDIM 256
#define NVOCAB 26
#define STR 264

// ---- workspace layout (float offsets) ----
#define OFF_BSUM  16
#define OFF_Z1    (OFF_BSUM+1024)
#define OFF_HH1   (OFF_Z1+1024)
#define OFF_H1    (OFF_HH1+1024)
#define OFF_C1    (OFF_H1+256)
#define OFF_WCH1  (OFF_C1+256)
#define OFF_BTF   (OFF_WCH1+256)
#define OFF_EWC   (OFF_BTF+256)          // [26][256] f32
#define OFF_P8    (OFF_EWC+6656)         // [26][1024] f32
#define OFF_SCB   (OFF_P8+26624)         // [32][256] ushort (scomb bf16)
#define OFF_O8B   (OFF_SCB+4096)         // [32][256] ushort (out8 bf16)
#define OFF_H2B   (OFF_O8B+4096)         // [32][256] ushort (h2 per child0-id)
#define OFF_C2T   (OFF_H2B+4096)         // [32][256] f32
#define OFF_HH2A  (OFF_C2T+8192)         // [32][1024] f32 (bsum + W_hh@h2)
#define OFF_H3B   (OFF_HH2A+32768)       // [704][256] ushort (h3 per (id0,id1))
#define OFF_C3T   (OFF_H3B+90112)        // [704][256] f32
#define OFF_HH3   (OFF_C3T+180224)       // [704][1024] f32 (bsum + W_hh@h3)
#define OFF_FRAG  (OFF_HH3+720896)       // ushort frag tables
#define OFF_SLABS (OFF_FRAG+327680)

__device__ __forceinline__ float sigmf(float x){ return 1.0f/(1.0f+__expf(-x)); }
__device__ __forceinline__ float tanhfast(float x){ return 1.0f - 2.0f/(__expf(2.0f*x)+1.0f); }
__device__ __forceinline__ ushort f2b(float x){ bf16 h = __float2bfloat16(x); return *(ushort*)&h; }
__device__ __forceinline__ float ldin(const void* p, int i, int f32){
  if (f32) return ((const float*)p)[i];
  unsigned int w = ((unsigned int)((const ushort*)p)[i]) << 16;
  return __uint_as_float(w);
}
__device__ __forceinline__ void ld8(const void* p, int i, int f32, float* o){
  if (f32){
    float4 a = *(const float4*)((const float*)p + i);
    float4 b = *(const float4*)((const float*)p + i + 4);
    o[0]=a.x;o[1]=a.y;o[2]=a.z;o[3]=a.w;o[4]=b.x;o[5]=b.y;o[6]=b.z;o[7]=b.w;
  } else {
    uint4 u = *(const uint4*)((const ushort*)p + i);
    unsigned w0=u.x,w1=u.y,w2=u.z,w3=u.w;
    o[0]=__uint_as_float(w0<<16); o[1]=__uint_as_float(w0&0xFFFF0000u);
    o[2]=__uint_as_float(w1<<16); o[3]=__uint_as_float(w1&0xFFFF0000u);
    o[4]=__uint_as_float(w2<<16); o[5]=__uint_as_float(w2&0xFFFF0000u);
    o[6]=__uint_as_float(w3<<16); o[7]=__uint_as_float(w3&0xFFFF0000u);
  }
}
__device__ __forceinline__ uint4 pack8(const ushort* h){
  uint4 u;
  u.x = (unsigned)h[0] | ((unsigned)h[1]<<16);
  u.y = (unsigned)h[2] | ((unsigned)h[3]<<16);
  u.z = (unsigned)h[4] | ((unsigned)h[5]<<16);
  u.w = (unsigned)h[6] | ((unsigned)h[7]<<16);
  return u;
}

__global__ void init_kernel(int* wsI){ if (threadIdx.x<4) wsI[threadIdx.x]=0; }

__global__ __launch_bounds__(256) void detect_kernel(int* wsI, const uint4* wih4){
  int c=0;
  for (int i = blockIdx.x*blockDim.x + threadIdx.x; i < 32768; i += gridDim.x*blockDim.x){
    uint4 u = wih4[i];
    unsigned w[4] = {u.x,u.y,u.z,u.w};
    #pragma unroll
    for (int j=0;j<4;j++){
      if ((w[j] & 0x7F80u) == 0x7F80u) c++;
      if ((w[j] & 0x7F800000u) == 0x7F800000u) c++;
    }
  }
  #pragma unroll
  for (int o=32;o>0;o>>=1) c += __shfl_xor(c,o,64);
  if ((threadIdx.x&63)==0 && c) atomicAdd(&wsI[1], c);
}

__global__ __launch_bounds__(256) void z1_kernel(
    float* __restrict__ wsf, const void* W_ih, const void* b_ih, const void* b_hh,
    const void* bt, const void* linit)
{
  const int f32 = ((const int*)wsf)[1] != 0;
  __shared__ float sx[256];
  int tid = threadIdx.x;
  int r = blockIdx.x*256 + tid;
  sx[tid] = ldin(linit, tid, f32);
  __syncthreads();
  float a = ldin(b_ih, r, f32) + ldin(b_hh, r, f32);
  wsf[OFF_BSUM + r] = a;
  float z = a;
  #pragma unroll 8
  for (int k=0;k<256;k+=8){
    float w[8]; ld8(W_ih, r*256+k, f32, w);
    #pragma unroll
    for (int j=0;j<8;j++) z += w[j]*sx[k+j];
  }
  wsf[OFF_Z1 + r] = z;
  if (blockIdx.x==0) wsf[OFF_BTF + tid] = ldin(bt, tid, f32);
}

__global__ __launch_bounds__(256) void h1_kernel(float* __restrict__ wsf){
  int e = threadIdx.x;
  float zi = wsf[OFF_Z1+e], zg = wsf[OFF_Z1+512+e], zo = wsf[OFF_Z1+768+e];
  float c1 = sigmf(zi)*tanhfast(zg);
  float h1 = sigmf(zo)*tanhfast(c1);
  wsf[OFF_H1+e]=h1; wsf[OFF_C1+e]=c1;
}

// blocks 0..3: hh1 rows; block 4: wch1 + scomb bf16 rows (needs EWC done)
__global__ __launch_bounds__(256) void hh1_kernel(float* __restrict__ wsf, const void* W_hh, const void* Wc){
  const int f32 = ((const int*)wsf)[1] != 0;
  __shared__ float sh1[256];
  int tid = threadIdx.x;
  sh1[tid] = wsf[OFF_H1+tid];
  __syncthreads();
  if (blockIdx.x < 4){
    int r = blockIdx.x*256 + tid;
    float z = wsf[OFF_BSUM + r];
    #pragma unroll 8
    for (int k=0;k<256;k+=8){
      float w[8]; ld8(W_hh, r*256+k, f32, w);
      #pragma unroll
      for (int j=0;j<8;j++) z += w[j]*sh1[k+j];
    }
    wsf[OFF_HH1 + r] = z;
  } else {
    float a = 0.f;
    #pragma unroll 8
    for (int k=0;k<256;k+=8){
      float w[8]; ld8(Wc, tid*512+k, f32, w);
      #pragma unroll
      for (int j=0;j<8;j++) a += w[j]*sh1[k+j];
    }
    wsf[OFF_WCH1 + tid] = a;
    ushort* SCB = (ushort*)(wsf + OFF_SCB);
    #pragma unroll 1
    for (int v32=0; v32<32; v32++){
      int v = v32 < NVOCAB ? v32 : NVOCAB-1;
      SCB[v32*256 + tid] = f2b(a + wsf[OFF_EWC + v*256 + tid]);
    }
  }
}

__global__ __launch_bounds__(256) void ewc_kernel(
    float* __restrict__ wsf, const void* Wc, const void* bc, const void* emb)
{
  const int f32 = ((const int*)wsf)[1] != 0;
  int v = blockIdx.x, i = threadIdx.x;
  __shared__ float se[256];
  se[i] = ldin(emb, v*256+i, f32);
  __syncthreads();
  float a = ldin(bc, i, f32);
  #pragma unroll 8
  for (int k=0;k<256;k+=8){
    float w[8]; ld8(Wc, i*512+256+k, f32, w);
    #pragma unroll
    for (int j=0;j<8;j++) a += w[j]*se[k+j];
  }
  wsf[OFF_EWC + v*256 + i] = a;
}

// A-fragment tables, vectorized: thread handles 8 consecutive k (one 16B store)
__global__ __launch_bounds__(256) void prep_kernel(
    float* __restrict__ wsf, const void* W_ih, const void* W_hh, const void* Wc, const void* Wt)
{
  const int f32 = ((const int*)wsf)[1] != 0;
  ushort* FWIH = (ushort*)(wsf + OFF_FRAG);
  ushort* FWHH = FWIH + 262144;
  ushort* FWC1 = FWHH + 262144;
  ushort* FWT  = FWC1 + 65536;
  int stride = gridDim.x*blockDim.x;
  int t0 = blockIdx.x*blockDim.x + threadIdx.x;
  for (int i=t0; i<32768; i+=stride){
    int c = i >> 6, L = i & 63;
    int mt = c>>3, ks = c&7;
    int m = (mt<<4) | (L&15);
    int k0 = (ks<<5) + ((L>>4)<<3);
    float w[8]; ushort h[8];
    ld8(W_ih, m*256+k0, f32, w);
    #pragma unroll
    for (int j=0;j<8;j++) h[j]=f2b(w[j]);
    *(uint4*)&FWIH[(c<<9)+(L<<3)] = pack8(h);
    ld8(W_hh, m*256+k0, f32, w);
    #pragma unroll
    for (int j=0;j<8;j++) h[j]=f2b(w[j]);
    *(uint4*)&FWHH[(c<<9)+(L<<3)] = pack8(h);
  }
  for (int i=t0; i<8192; i+=stride){
    int c = i >> 6, L = i & 63;
    int mt = c>>3, ks = c&7;
    int m = (mt<<4) | (L&15);
    int k0 = (ks<<5) + ((L>>4)<<3);
    float w[8]; ushort h[8];
    ld8(Wc, m*512+k0, f32, w);
    #pragma unroll
    for (int j=0;j<8;j++) h[j]=f2b(w[j]);
    *(uint4*)&FWC1[(c<<9)+(L<<3)] = pack8(h);
    ld8(Wt, m*256+k0, f32, w);
    #pragma unroll
    for (int j=0;j<8;j++) h[j]=f2b(w[j]);
    *(uint4*)&FWT[(c<<9)+(L<<3)] = pack8(h);
  }
}

// ---- tag8: tag = Wt@scomb + bt, log-softmax, out8 bf16 rows (26 vocab) ----
__global__ __launch_bounds__(256) void tag8_kernel(float* __restrict__ wsf){
  __shared__ float wred[4][16];
  const int tid=threadIdx.x, wv=tid>>6, lane=tid&63, ln15=lane&15, quad=lane>>4;
  const int nt = blockIdx.x;
  const ushort* FWT = (const ushort*)(wsf + OFF_FRAG) + 262144 + 262144 + 65536;
  const ushort* SCB = (const ushort*)(wsf + OFF_SCB);
  ushort* O8B = (ushort*)(wsf + OFF_O8B);
  const int row = nt*16 + ln15;

  f32x4 tg[4];
  #pragma unroll 1
  for (int p=0; p<4; p++){
    const int mt = wv*4 + p;
    tg[p] = (f32x4){0.f,0.f,0.f,0.f};
    #pragma unroll
    for (int ks=0; ks<8; ks++){
      bf16x8 a = *(const bf16x8*)&FWT[((mt*8+ks)<<9) + (lane<<3)];
      bf16x8 b = *(const bf16x8*)&SCB[row*256 + ks*32 + quad*8];
      tg[p] = __builtin_amdgcn_mfma_f32_16x16x32_bf16(a, b, tg[p], 0,0,0);
    }
    float4 bt4 = *(const float4*)&wsf[OFF_BTF + mt*16 + quad*4];
    #pragma unroll
    for (int r=0; r<4; r++) tg[p][r] += ((const float*)&bt4)[r];
  }

  float mx = -3.0e38f;
  #pragma unroll
  for (int p=0; p<4; p++)
    #pragma unroll
    for (int r=0; r<4; r++) mx = fmaxf(mx, tg[p][r]);
  mx = fmaxf(mx, __shfl_xor(mx, 16, 64));
  mx = fmaxf(mx, __shfl_xor(mx, 32, 64));
  wred[wv][ln15] = mx;
  __syncthreads();
  float gmx = fmaxf(fmaxf(wred[0][ln15], wred[1][ln15]), fmaxf(wred[2][ln15], wred[3][ln15]));
  __syncthreads();
  float s = 0.f;
  #pragma unroll
  for (int p=0; p<4; p++)
    #pragma unroll
    for (int r=0; r<4; r++) s += __expf(tg[p][r] - gmx);
  s += __shfl_xor(s, 16, 64);
  s += __shfl_xor(s, 32, 64);
  wred[wv][ln15] = s;
  __syncthreads();
  float gs = (wred[0][ln15]+wred[1][ln15]) + (wred[2][ln15]+wred[3][ln15]);
  float lz = gmx + __logf(gs);

  #pragma unroll
  for (int p=0; p<4; p++){
    int m = (wv*4+p)*16 + quad*4;
    ushort ob[4];
    #pragma unroll
    for (int r=0; r<4; r++) ob[r] = f2b(tg[p][r] - lz);
    uint2 uu;
    uu.x = (unsigned)ob[0] | ((unsigned)ob[1]<<16);
    uu.y = (unsigned)ob[2] | ((unsigned)ob[3]<<16);
    *(uint2*)&O8B[row*256 + m] = uu;
  }
}

// ---- p8: P8[v] = W_ih @ out8[v] via MFMA ----
__global__ __launch_bounds__(64) void p8_kernel(float* __restrict__ wsf){
  const int nt = blockIdx.x >> 4, eb = blockIdx.x & 15;
  const int lane = threadIdx.x, ln15 = lane & 15, quad = lane >> 4;
  const ushort* FWIH = (const ushort*)(wsf + OFF_FRAG);
  const ushort* O8B  = (const ushort*)(wsf + OFF_O8B);
  const int row = nt*16 + ln15;

  f32x4 acc[4];
  #pragma unroll
  for (int g=0; g<4; g++) acc[g] = (f32x4){0.f,0.f,0.f,0.f};
  #pragma unroll
  for (int ks=0; ks<8; ks++){
    bf16x8 b = *(const bf16x8*)&O8B[row*256 + ks*32 + quad*8];
    #pragma unroll
    for (int g=0; g<4; g++){
      int mt = g*16 + eb;
      bf16x8 a = *(const bf16x8*)&FWIH[((mt*8+ks)<<9) + (lane<<3)];
      acc[g] = __builtin_amdgcn_mfma_f32_16x16x32_bf16(a, b, acc[g], 0,0,0);
    }
  }
  if (row < NVOCAB){
    #pragma unroll
    for (int g=0; g<4; g++)
      *(float4*)&wsf[OFF_P8 + row*1024 + g*256 + eb*16 + quad*4] =
        (float4){acc[g][0], acc[g][1], acc[g][2], acc[g][3]};
  }
}

// ---- t2 table: (h2,c2)[a] = gate(hh1 + P8[a], cp=C1), a<26 ----
__global__ __launch_bounds__(256) void t2tab_kernel(float* __restrict__ wsf){
  int a = blockIdx.x, e = threadIdx.x;
  const float* P8a = wsf + OFF_P8 + (size_t)a*1024;
  float zi = wsf[OFF_HH1+e]     + P8a[e];
  float zf = wsf[OFF_HH1+256+e] + P8a[256+e];
  float zg = wsf[OFF_HH1+512+e] + P8a[512+e];
  float zo = wsf[OFF_HH1+768+e] + P8a[768+e];
  float cn = sigmf(zf)*wsf[OFF_C1+e] + sigmf(zi)*tanhfast(zg);
  ((ushort*)(wsf+OFF_H2B))[a*256+e] = f2b(sigmf(zo)*tanhfast(cn));
  wsf[OFF_C2T + a*256 + e] = cn;
}

// ---- hhmat: Out[r] = bsum + W_hh @ Hrows[r]  (MFMA, grid = ceil(R/16)*16 x 64) ----
__global__ __launch_bounds__(64) void hhmat_kernel(
    float* __restrict__ wsf, const ushort* __restrict__ Hrows,
    float* __restrict__ Out, int R)
{
  const int nt = blockIdx.x >> 4, eb = blockIdx.x & 15;
  const int lane = threadIdx.x, ln15 = lane & 15, quad = lane >> 4;
  const ushort* FWHH = (const ushort*)(wsf + OFF_FRAG) + 262144;
  int row = nt*16 + ln15;
  int rowc = row < R ? row : R-1;

  f32x4 acc[4];
  #pragma unroll
  for (int g=0; g<4; g++) acc[g] = (f32x4){0.f,0.f,0.f,0.f};
  #pragma unroll
  for (int ks=0; ks<8; ks++){
    bf16x8 b = *(const bf16x8*)&Hrows[rowc*256 + ks*32 + quad*8];
    #pragma unroll
    for (int g=0; g<4; g++){
      int mt = g*16 + eb;
      bf16x8 a = *(const bf16x8*)&FWHH[((mt*8+ks)<<9) + (lane<<3)];
      acc[g] = __builtin_amdgcn_mfma_f32_16x16x32_bf16(a, b, acc[g], 0,0,0);
    }
  }
  if (row < R){
    #pragma unroll
    for (int g=0; g<4; g++){
      int m = g*256 + eb*16 + quad*4;
      float4 bs = *(const float4*)&wsf[OFF_BSUM + m];
      *(float4*)&Out[(size_t)row*1024 + m] =
        (float4){acc[g][0]+bs.x, acc[g][1]+bs.y, acc[g][2]+bs.z, acc[g][3]+bs.w};
    }
  }
}

// ---- t3 table: (h3,c3)[a*26+b] = gate(HH2A[a] + P8[b], cp=C2[a]) ----
__global__ __launch_bounds__(256) void t3tab_kernel(float* __restrict__ wsf){
  int p = blockIdx.x;
  int a = p / 26, b = p - a*26;
  int e = threadIdx.x;
  const float* HA = wsf + OFF_HH2A + (size_t)a*1024;
  const float* PB = wsf + OFF_P8   + (size_t)b*1024;
  float zi = HA[e]     + PB[e];
  float zf = HA[256+e] + PB[256+e];
  float zg = HA[512+e] + PB[512+e];
  float zo = HA[768+e] + PB[768+e];
  float cn = sigmf(zf)*wsf[OFF_C2T + a*256 + e] + sigmf(zi)*tanhfast(zg);
  ((ushort*)(wsf+OFF_H3B))[p*256+e] = f2b(sigmf(zo)*tanhfast(cn));
  wsf[OFF_C3T + p*256 + e] = cn;
}

// ---- level-7 kernel: t1/t2 tabulated; t3 = gather-gate, t4 = one W_hh MFMA ----
__global__ __launch_bounds__(1024) void level7_kernel(
    const float* __restrict__ wsf, const int* __restrict__ idents,
    int offL, int offC, int nNodes, int nChild, ushort* __restrict__ OutNext)
{
  __shared__ __align__(16) ushort Hlds[2][16*STR];
  __shared__ float wred[16][16];
  __shared__ int sid[16], sid4[64];
  const int tid=threadIdx.x, wv=tid>>6, lane=tid&63, ln15=lane&15, quad=lane>>4;
  const int j0 = blockIdx.x*16;
  const ushort* FWHH = (const ushort*)(wsf+OFF_FRAG)+262144;
  const ushort* FWC1 = FWHH+262144;
  const ushort* FWT  = FWC1+65536;
  const float* P8 = wsf+OFF_P8;
  const float* EWcP = wsf+OFF_EWC;

  if (tid<16){ int nd=j0+tid; if(nd>=nNodes) nd=nNodes-1; sid[tid]=idents[offL+nd]; }
  if (tid<64){ int ci=j0*4+tid; if(ci>=nChild) ci=nChild-1; sid4[tid]=idents[offC+ci]; }
  __syncthreads();

  const int eb = wv*16;
  const int ia=sid4[ln15*4], ib=sid4[ln15*4+1], ic=sid4[ln15*4+2], idd=sid4[ln15*4+3];
  const int pp = ia*26+ib;

  f32x4 creg;
  // t3: z = HH3[pp] + P8[ic], cp = C3[pp]  (no MFMA)
  {
    const float* HH3p = wsf + OFF_HH3 + (size_t)pp*1024;
    const float* P8c  = P8 + (size_t)ic*1024;
    float4 cp4 = *(const float4*)&wsf[OFF_C3T + (size_t)pp*256 + eb + quad*4];
    float z[4][4];
    #pragma unroll
    for (int g=0; g<4; g++){
      float4 hv = *(const float4*)&HH3p[g*256 + eb + quad*4];
      float4 pv = *(const float4*)&P8c[g*256 + eb + quad*4];
      z[g][0]=hv.x+pv.x; z[g][1]=hv.y+pv.y; z[g][2]=hv.z+pv.z; z[g][3]=hv.w+pv.w;
    }
    ushort hb[4];
    #pragma unroll
    for (int r=0; r<4; r++){
      float cn = sigmf(z[1][r])*((const float*)&cp4)[r] + sigmf(z[0][r])*tanhfast(z[2][r]);
      creg[r]=cn;
      hb[r]=f2b(sigmf(z[3][r])*tanhfast(cn));
    }
    uint2 uu;
    uu.x = (unsigned)hb[0] | ((unsigned)hb[1]<<16);
    uu.y = (unsigned)hb[2] | ((unsigned)hb[3]<<16);
    *(uint2*)&Hlds[0][ln15*STR + eb + quad*4] = uu;
  }
  __syncthreads();

  // t4: z = W_hh@h4 + bsum + P8[idd]
  {
    f32x4 acc[4];
    #pragma unroll
    for (int g=0; g<4; g++) acc[g] = (f32x4){0.f,0.f,0.f,0.f};
    #pragma unroll
    for (int ks=0; ks<8; ks++){
      bf16x8 bh = *(const bf16x8*)&Hlds[0][ln15*STR + ks*32 + quad*8];
      #pragma unroll
      for (int g=0; g<4; g++){
        bf16x8 a = *(const bf16x8*)&FWHH[(((g*16+wv)*8+ks)<<9) + (lane<<3)];
        acc[g] = __builtin_amdgcn_mfma_f32_16x16x32_bf16(a, bh, acc[g], 0,0,0);
      }
    }
    const float* P8d = P8 + (size_t)idd*1024;
    #pragma unroll
    for (int g=0; g<4; g++){
      float4 bg = *(const float4*)&wsf[OFF_BSUM + g*256 + eb + quad*4];
      float4 xg = *(const float4*)&P8d[g*256 + eb + quad*4];
      acc[g][0]+=bg.x+xg.x; acc[g][1]+=bg.y+xg.y; acc[g][2]+=bg.z+xg.z; acc[g][3]+=bg.w+xg.w;
    }
    ushort hb[4];
    #pragma unroll
    for (int r=0; r<4; r++){
      float cn = sigmf(acc[1][r])*creg[r] + sigmf(acc[0][r])*tanhfast(acc[2][r]);
      hb[r]=f2b(sigmf(acc[3][r])*tanhfast(cn));
    }
    uint2 uu;
    uu.x = (unsigned)hb[0] | ((unsigned)hb[1]<<16);
    uu.y = (unsigned)hb[2] | ((unsigned)hb[3]<<16);
    *(uint2*)&Hlds[1][ln15*STR + eb + quad*4] = uu;
  }
  __syncthreads();

  // combine = Wc1@h5 + EWc[id]  (h5 in Hlds[1] -> comb in Hlds[0])
  {
    f32x4 ac = (f32x4){0.f,0.f,0.f,0.f};
    #pragma unroll
    for (int ks=0; ks<8; ks++){
      bf16x8 a = *(const bf16x8*)&FWC1[((wv*8+ks)<<9) + (lane<<3)];
      bf16x8 b = *(const bf16x8*)&Hlds[1][ln15*STR + ks*32 + quad*8];
      ac = __builtin_amdgcn_mfma_f32_16x16x32_bf16(a, b, ac, 0,0,0);
    }
    float4 ew = *(const float4*)&EWcP[(size_t)sid[ln15]*256 + wv*16 + quad*4];
    ushort cb[4];
    #pragma unroll
    for (int r=0; r<4; r++) cb[r] = f2b(ac[r] + ((const float*)&ew)[r]);
    uint2 uu;
    uu.x = (unsigned)cb[0] | ((unsigned)cb[1]<<16);
    uu.y = (unsigned)cb[2] | ((unsigned)cb[3]<<16);
    *(uint2*)&Hlds[0][ln15*STR + wv*16 + quad*4] = uu;
  }
  __syncthreads();

  // tag = Wt@comb + bt
  f32x4 tg = (f32x4){0.f,0.f,0.f,0.f};
  #pragma unroll
  for (int ks=0; ks<8; ks++){
    bf16x8 a = *(const bf16x8*)&FWT[((wv*8+ks)<<9) + (lane<<3)];
    bf16x8 b = *(const bf16x8*)&Hlds[0][ln15*STR + ks*32 + quad*8];
    tg = __builtin_amdgcn_mfma_f32_16x16x32_bf16(a, b, tg, 0,0,0);
  }
  {
    float4 bt4 = *(const float4*)&wsf[OFF_BTF + wv*16 + quad*4];
    #pragma unroll
    for (int r=0; r<4; r++) tg[r] += ((const float*)&bt4)[r];
  }

  // log-softmax over 256 rows (16 wave partials)
  float mx = fmaxf(fmaxf(tg[0],tg[1]), fmaxf(tg[2],tg[3]));
  mx = fmaxf(mx, __shfl_xor(mx, 16, 64));
  mx = fmaxf(mx, __shfl_xor(mx, 32, 64));
  wred[wv][ln15] = mx;
  __syncthreads();
  float gmx = wred[0][ln15];
  #pragma unroll
  for (int w=1; w<16; w++) gmx = fmaxf(gmx, wred[w][ln15]);
  __syncthreads();
  float s = __expf(tg[0]-gmx) + __expf(tg[1]-gmx) + __expf(tg[2]-gmx) + __expf(tg[3]-gmx);
  s += __shfl_xor(s, 16, 64);
  s += __shfl_xor(s, 32, 64);
  wred[wv][ln15] = s;
  __syncthreads();
  float gs = 0.f;
  #pragma unroll
  for (int w=0; w<16; w++) gs += wred[w][ln15];
  float lz = gmx + __logf(gs);

  int node = j0 + ln15;
  if (node < nNodes){
    ushort ob[4];
    #pragma unroll
    for (int r=0; r<4; r++) ob[r] = f2b(tg[r] - lz);
    uint2 uu;
    uu.x = (unsigned)ob[0] | ((unsigned)ob[1]<<16);
    uu.y = (unsigned)ob[2] | ((unsigned)ob[3]<<16);
    *(uint2*)&OutNext[(size_t)node*256 + wv*16 + quad*4] = uu;
  }
}

// ---- fused level kernel (L6): 16 nodes/block, 16 waves ----
template<int NT, bool GATHER>
__global__ __launch_bounds__(1024) void level_kernel(
    const float* __restrict__ wsf, const ushort* __restrict__ OutPrev,
    const int* __restrict__ idents, int offL, int offC, int nNodes, int nChild,
    ushort* __restrict__ OutNext)
{
  constexpr int NN = NT*16;
  __shared__ __align__(16) ushort Hlds[2][NN*STR];
  __shared__ __align__(16) ushort Xlds[GATHER ? 16 : NN*STR];
  __shared__ float wred[16][NN];
  __shared__ int sid[NN];
  __shared__ int sid4[GATHER ? NN*4 : 4];

  const int tid  = threadIdx.x;
  const int wv   = tid >> 6;
  const int lane = tid & 63;
  const int ln15 = lane & 15;
  const int quad = lane >> 4;
  const int j0   = blockIdx.x * NN;

  const ushort* FWIH = (const ushort*)(wsf + OFF_FRAG);
  const ushort* FWHH = FWIH + 262144;
  const ushort* FWC1 = FWHH + 262144;
  const ushort* FWT  = FWC1 + 65536;
  const float*  P8   = wsf + OFF_P8;
  const float*  EWcP = wsf + OFF_EWC;

  if (tid<NN){ int nd=j0+tid; if (nd>=nNodes) nd=nNodes-1; sid[tid]=idents[offL+nd]; }
  if (GATHER){
    for (int i=tid; i<NN*4; i+=1024){
      int ci = j0*4 + i; if (ci >= nChild) ci = nChild-1;
      sid4[i] = idents[offC + ci];
    }
  }

  f32x4 creg[NT];

  #pragma unroll 1
  for (int t=1; t<=4; t++){
    if (!GATHER){
      for (int i=tid; i<NN*32; i+=1024){
        int n = i>>5, off = i&31;
        int node = j0+n; if (node>=nNodes) node=nNodes-1;
        uint4 v = ((const uint4*)OutPrev)[((size_t)node*4 + (t-1))*32 + off];
        *(uint4*)&Xlds[n*STR + off*8] = v;
      }
    }
    __syncthreads();
    const int rb = (t-1)&1, wb = t&1;

    f32x4 acc[4][NT];
    #pragma unroll
    for (int g=0; g<4; g++)
      #pragma unroll
      for (int n=0; n<NT; n++) acc[g][n] = (f32x4){0.f,0.f,0.f,0.f};

    if (t>=2){
      #pragma unroll
      for (int ks=0; ks<8; ks++){
        bf16x8 bh[NT];
        #pragma unroll
        for (int n=0; n<NT; n++)
          bh[n] = *(const bf16x8*)&Hlds[rb][(n*16+ln15)*STR + ks*32 + quad*8];
        #pragma unroll
        for (int g=0; g<4; g++){
          int mt = g*16 + wv;
          bf16x8 a = *(const bf16x8*)&FWHH[((mt*8+ks)<<9) + (lane<<3)];
          #pragma unroll
          for (int n=0; n<NT; n++)
            acc[g][n] = __builtin_amdgcn_mfma_f32_16x16x32_bf16(a, bh[n], acc[g][n], 0,0,0);
        }
      }
    }
    if (!GATHER){
      #pragma unroll
      for (int ks=0; ks<8; ks++){
        bf16x8 bx[NT];
        #pragma unroll
        for (int n=0; n<NT; n++)
          bx[n] = *(const bf16x8*)&Xlds[(n*16+ln15)*STR + ks*32 + quad*8];
        #pragma unroll
        for (int g=0; g<4; g++){
          int mt = g*16 + wv;
          bf16x8 a = *(const bf16x8*)&FWIH[((mt*8+ks)<<9) + (lane<<3)];
          #pragma unroll
          for (int n=0; n<NT; n++)
            acc[g][n] = __builtin_amdgcn_mfma_f32_16x16x32_bf16(a, bx[n], acc[g][n], 0,0,0);
        }
      }
    }

    const float* baseP = wsf + ((t==1) ? OFF_HH1 : OFF_BSUM);
    const int eb = wv*16;
    #pragma unroll
    for (int g=0; g<4; g++){
      float4 bg = *(const float4*)&baseP[g*256 + eb + quad*4];
      #pragma unroll
      for (int n=0; n<NT; n++){
        acc[g][n][0]+=bg.x; acc[g][n][1]+=bg.y; acc[g][n][2]+=bg.z; acc[g][n][3]+=bg.w;
      }
    }
    if (GATHER){
      #pragma unroll
      for (int n=0; n<NT; n++){
        const float* pg = P8 + (size_t)sid4[(n*16+ln15)*4 + (t-1)]*1024;
        #pragma unroll
        for (int g=0; g<4; g++){
          float4 xg = *(const float4*)&pg[g*256 + eb + quad*4];
          acc[g][n][0]+=xg.x; acc[g][n][1]+=xg.y; acc[g][n][2]+=xg.z; acc[g][n][3]+=xg.w;
        }
      }
    }
    #pragma unroll
    for (int n=0; n<NT; n++){
      f32x4 cp;
      if (t==1){
        float4 cc = *(const float4*)&wsf[OFF_C1 + eb + quad*4];
        cp = (f32x4){cc.x,cc.y,cc.z,cc.w};
      } else cp = creg[n];
      ushort hb[4];
      #pragma unroll
      for (int r=0; r<4; r++){
        float cn = sigmf(acc[1][n][r])*cp[r] + sigmf(acc[0][n][r])*tanhfast(acc[2][n][r]);
        creg[n][r] = cn;
        hb[r] = f2b(sigmf(acc[3][n][r])*tanhfast(cn));
      }
      uint2 uu;
      uu.x = (unsigned)hb[0] | ((unsigned)hb[1]<<16);
      uu.y = (unsigned)hb[2] | ((unsigned)hb[3]<<16);
      *(uint2*)&Hlds[wb][(n*16+ln15)*STR + eb + quad*4] = uu;
    }
    __syncthreads();
  }

  // combined = Wc1@h + EWc[id]
  {
    f32x4 ac[NT];
    #pragma unroll
    for (int n=0; n<NT; n++) ac[n] = (f32x4){0.f,0.f,0.f,0.f};
    #pragma unroll
    for (int ks=0; ks<8; ks++){
      bf16x8 a = *(const bf16x8*)&FWC1[((wv*8+ks)<<9) + (lane<<3)];
      #pragma unroll
      for (int n=0; n<NT; n++){
        bf16x8 b = *(const bf16x8*)&Hlds[0][(n*16+ln15)*STR + ks*32 + quad*8];
        ac[n] = __builtin_amdgcn_mfma_f32_16x16x32_bf16(a, b, ac[n], 0,0,0);
      }
    }
    #pragma unroll
    for (int n=0; n<NT; n++){
      float4 ew = *(const float4*)&EWcP[(size_t)sid[n*16+ln15]*256 + wv*16 + quad*4];
      ushort cb[4];
      #pragma unroll
      for (int r=0; r<4; r++) cb[r] = f2b(ac[n][r] + ((const float*)&ew)[r]);
      uint2 uu;
      uu.x = (unsigned)cb[0] | ((unsigned)cb[1]<<16);
      uu.y = (unsigned)cb[2] | ((unsigned)cb[3]<<16);
      *(uint2*)&Hlds[1][(n*16+ln15)*STR + wv*16 + quad*4] = uu;
    }
  }
  __syncthreads();

  // tag = Wt@combined + bt
  f32x4 tg[NT];
  {
    #pragma unroll
    for (int n=0; n<NT; n++) tg[n] = (f32x4){0.f,0.f,0.f,0.f};
    #pragma unroll
    for (int ks=0; ks<8; ks++){
      bf16x8 a = *(const bf16x8*)&FWT[((wv*8+ks)<<9) + (lane<<3)];
      #pragma unroll
      for (int n=0; n<NT; n++){
        bf16x8 b = *(const bf16x8*)&Hlds[1][(n*16+ln15)*STR + ks*32 + quad*8];
        tg[n] = __builtin_amdgcn_mfma_f32_16x16x32_bf16(a, b, tg[n], 0,0,0);
      }
    }
    float4 bt4 = *(const float4*)&wsf[OFF_BTF + wv*16 + quad*4];
    #pragma unroll
    for (int n=0; n<NT; n++)
      #pragma unroll
      for (int r=0; r<4; r++) tg[n][r] += ((const float*)&bt4)[r];
  }

  float gmx[NT], gs[NT];
  {
    #pragma unroll
    for (int n=0; n<NT; n++){
      float mx = fmaxf(fmaxf(tg[n][0],tg[n][1]), fmaxf(tg[n][2],tg[n][3]));
      mx = fmaxf(mx, __shfl_xor(mx, 16, 64));
      mx = fmaxf(mx, __shfl_xor(mx, 32, 64));
      wred[wv][n*16+ln15] = mx;
    }
    __syncthreads();
    #pragma unroll
    for (int n=0; n<NT; n++){
      float m = wred[0][n*16+ln15];
      #pragma unroll
      for (int w=1; w<16; w++) m = fmaxf(m, wred[w][n*16+ln15]);
      gmx[n] = m;
    }
    __syncthreads();
    #pragma unroll
    for (int n=0; n<NT; n++){
      float s = __expf(tg[n][0]-gmx[n]) + __expf(tg[n][1]-gmx[n])
              + __expf(tg[n][2]-gmx[n]) + __expf(tg[n][3]-gmx[n]);
      s += __shfl_xor(s, 16, 64);
      s += __shfl_xor(s, 32, 64);
      wred[wv][n*16+ln15] = s;
    }
    __syncthreads();
    #pragma unroll
    for (int n=0; n<NT; n++){
      float s = 0.f;
      #pragma unroll
      for (int w=0; w<16; w++) s += wred[w][n*16+ln15];
      gs[n] = s;
    }
  }

  #pragma unroll
  for (int n=0; n<NT; n++){
    int node = j0 + n*16 + ln15;
    if (node >= nNodes) continue;
    float lz = gmx[n] + __logf(gs[n]);
    ushort ob[4];
    #pragma unroll
    for (int r=0; r<4; r++) ob[r] = f2b(tg[n][r] - lz);
    uint2 uu;
    uu.x = (unsigned)ob[0] | ((unsigned)ob[1]<<16);
    uu.y = (unsigned)ob[2] | ((unsigned)ob[3]<<16);
    *(uint2*)&OutNext[(size_t)node*256 + wv*16 + quad*4] = uu;
  }
}

// ---- one LSTM t-step for small levels: M-parallel across the grid ----
template<bool FIRST>
__global__ __launch_bounds__(64) void step_kernel(
    const float* __restrict__ wsf, const ushort* __restrict__ OutPrev,
    const ushort* __restrict__ Hin, ushort* __restrict__ Hout,
    float* __restrict__ Cbuf, int nNodes, int tm1)
{
  const int nt   = blockIdx.x >> 4;
  const int eb   = blockIdx.x & 15;
  const int lane = threadIdx.x;
  const int ln15 = lane & 15;
  const int quad = lane >> 4;

  const ushort* FWIH = (const ushort*)(wsf + OFF_FRAG);
  const ushort* FWHH = FWIH + 262144;

  int node = nt*16 + ln15; if (node >= nNodes) node = nNodes-1;
  const int rowX = (node*4 + tm1) * 256;
  const int rowH = node * 256;

  f32x4 acc[4];
  #pragma unroll
  for (int g=0; g<4; g++) acc[g] = (f32x4){0.f,0.f,0.f,0.f};

  #pragma unroll
  for (int ks=0; ks<8; ks++){
    bf16x8 bx = *(const bf16x8*)&OutPrev[rowX + ks*32 + quad*8];
    bf16x8 bh;
    if (!FIRST) bh = *(const bf16x8*)&Hin[rowH + ks*32 + quad*8];
    #pragma unroll
    for (int g=0; g<4; g++){
      int mt = g*16 + eb;
      bf16x8 a = *(const bf16x8*)&FWIH[((mt*8+ks)<<9) + (lane<<3)];
      acc[g] = __builtin_amdgcn_mfma_f32_16x16x32_bf16(a, bx, acc[g], 0,0,0);
      if (!FIRST){
        bf16x8 a2 = *(const bf16x8*)&FWHH[((mt*8+ks)<<9) + (lane<<3)];
        acc[g] = __builtin_amdgcn_mfma_f32_16x16x32_bf16(a2, bh, acc[g], 0,0,0);
      }
    }
  }

  const float* baseP = wsf + (FIRST ? OFF_HH1 : OFF_BSUM);
  const int e0 = eb*16 + quad*4;
  float4 b0 = *(const float4*)&baseP[       e0];
  float4 b1 = *(const float4*)&baseP[ 256 + e0];
  float4 b2 = *(const float4*)&baseP[ 512 + e0];
  float4 b3 = *(const float4*)&baseP[ 768 + e0];
  float4 cp;
  if (FIRST) cp = *(const float4*)&wsf[OFF_C1 + e0];
  else       cp = *(const float4*)&Cbuf[rowH + e0];

  float cn4[4]; ushort hb[4];
  #pragma unroll
  for (int r=0; r<4; r++){
    float zi = acc[0][r] + ((const float*)&b0)[r];
    float zf = acc[1][r] + ((const float*)&b1)[r];
    float zg = acc[2][r] + ((const float*)&b2)[r];
    float zo = acc[3][r] + ((const float*)&b3)[r];
    float cn = sigmf(zf)*((const float*)&cp)[r] + sigmf(zi)*tanhfast(zg);
    cn4[r] = cn;
    hb[r] = f2b(sigmf(zo)*tanhfast(cn));
  }
  *(float4*)&Cbuf[rowH + e0] = (float4){cn4[0],cn4[1],cn4[2],cn4[3]};
  uint2 uu;
  uu.x = (unsigned)hb[0] | ((unsigned)hb[1]<<16);
  uu.y = (unsigned)hb[2] | ((unsigned)hb[3]<<16);
  *(uint2*)&Hout[rowH + e0] = uu;
}

// ---- epilogue for small levels: combine -> tag -> log-softmax -> out ----
template<bool FINAL>
__global__ __launch_bounds__(256) void fin_kernel(
    const float* __restrict__ wsf, const ushort* __restrict__ Hfin,
    const int* __restrict__ idents, int offL, int nNodes,
    ushort* __restrict__ OutNext, void* __restrict__ dout)
{
  __shared__ __align__(16) ushort Clds[16*STR];
  __shared__ float wred[4][16];
  const int tid  = threadIdx.x;
  const int wv   = tid >> 6;
  const int lane = tid & 63;
  const int ln15 = lane & 15;
  const int quad = lane >> 4;
  const int nt   = blockIdx.x;

  const ushort* FWIH = (const ushort*)(wsf + OFF_FRAG);
  const ushort* FWC1 = FWIH + 262144 + 262144;
  const ushort* FWT  = FWC1 + 65536;
  const float*  EWcP = wsf + OFF_EWC;

  int node = nt*16 + ln15; if (node >= nNodes) node = nNodes-1;
  const int myid = idents[offL + node];
  const int rowH = node * 256;

  #pragma unroll 1
  for (int p=0; p<4; p++){
    const int mt = wv*4 + p;
    f32x4 ac = (f32x4){0.f,0.f,0.f,0.f};
    #pragma unroll
    for (int ks=0; ks<8; ks++){
      bf16x8 a = *(const bf16x8*)&FWC1[((mt*8+ks)<<9) + (lane<<3)];
      bf16x8 b = *(const bf16x8*)&Hfin[rowH + ks*32 + quad*8];
      ac = __builtin_amdgcn_mfma_f32_16x16x32_bf16(a, b, ac, 0,0,0);
    }
    float4 ew = *(const float4*)&EWcP[(size_t)myid*256 + mt*16 + quad*4];
    ushort cb[4];
    #pragma unroll
    for (int r=0; r<4; r++) cb[r] = f2b(ac[r] + ((const float*)&ew)[r]);
    uint2 uu;
    uu.x = (unsigned)cb[0] | ((unsigned)cb[1]<<16);
    uu.y = (unsigned)cb[2] | ((unsigned)cb[3]<<16);
    *(uint2*)&Clds[ln15*STR + mt*16 + quad*4] = uu;
  }
  __syncthreads();

  f32x4 tg[4];
  #pragma unroll 1
  for (int p=0; p<4; p++){
    const int mt = wv*4 + p;
    tg[p] = (f32x4){0.f,0.f,0.f,0.f};
    #pragma unroll
    for (int ks=0; ks<8; ks++){
      bf16x8 a = *(const bf16x8*)&FWT[((mt*8+ks)<<9) + (lane<<3)];
      bf16x8 b = *(const bf16x8*)&Clds[ln15*STR + ks*32 + quad*8];
      tg[p] = __builtin_amdgcn_mfma_f32_16x16x32_bf16(a, b, tg[p], 0,0,0);
    }
    float4 bt4 = *(const float4*)&wsf[OFF_BTF + mt*16 + quad*4];
    #pragma unroll
    for (int r=0; r<4; r++) tg[p][r] += ((const float*)&bt4)[r];
  }

  float mx = -3.0e38f;
  #pragma unroll
  for (int p=0; p<4; p++)
    #pragma unroll
    for (int r=0; r<4; r++) mx = fmaxf(mx, tg[p][r]);
  mx = fmaxf(mx, __shfl_xor(mx, 16, 64));
  mx = fmaxf(mx, __shfl_xor(mx, 32, 64));
  wred[wv][ln15] = mx;
  __syncthreads();
  float gmx = fmaxf(fmaxf(wred[0][ln15], wred[1][ln15]), fmaxf(wred[2][ln15], wred[3][ln15]));
  __syncthreads();
  float s = 0.f;
  #pragma unroll
  for (int p=0; p<4; p++)
    #pragma unroll
    for (int r=0; r<4; r++) s += __expf(tg[p][r] - gmx);
  s += __shfl_xor(s, 16, 64);
  s += __shfl_xor(s, 32, 64);
  wred[wv][ln15] = s;
  __syncthreads();
  float gs = (wred[0][ln15]+wred[1][ln15]) + (wred[2][ln15]+wred[3][ln15]);
  float lz = gmx + __logf(gs);

  if (FINAL){
    if (ln15 == 0){
      const int f32o = ((const int*)wsf)[1] != 0;
      #pragma unroll
      for (int p=0; p<4; p++){
        #pragma unroll
        for (int r=0; r<4; r++){
          int m = (wv*4+p)*16 + quad*4 + r;
          float v = tg[p][r] - lz;
          if (f32o) ((float*)dout)[m] = v;
          else      ((ushort*)dout)[m] = f2b(v);
        }
      }
    }
    return;
  }
  int onode = nt*16 + ln15;
  if (onode < nNodes){
    #pragma unroll
    for (int p=0; p<4; p++){
      int m = (wv*4+p)*16 + quad*4;
      ushort ob[4];
      #pragma unroll
      for (int r=0; r<4; r++) ob[r] = f2b(tg[p][r] - lz);
      uint2 uu;
      uu.x = (unsigned)ob[0] | ((unsigned)ob[1]<<16);
      uu.y = (unsigned)ob[2] | ((unsigned)ob[3]<<16);
      *(uint2*)&OutNext[(size_t)onode*256 + m] = uu;
    }
  }
}

extern "C" void kernel_launch(void* const* d_in, const int* in_sizes, int n_in,
                              void* d_out, int out_size, void* d_ws, size_t ws_size,
                              hipStream_t stream)
{
  (void)in_sizes; (void)n_in; (void)out_size; (void)ws_size;
  const int* idents = (const int*)d_in[0];
  const void* emb   = d_in[1];
  const void* W_ih  = d_in[2];
  const void* W_hh  = d_in[3];
  const void* b_ih  = d_in[4];
  const void* b_hh  = d_in[5];
  const void* Wc    = d_in[6];
  const void* bc    = d_in[7];
  const void* Wt    = d_in[8];
  const void* bt    = d_in[9];
  const void* linit = d_in[10];

  float* wsf = (float*)d_ws;
  ushort* slabA = (ushort*)(wsf + OFF_SLABS);
  ushort* slabB = slabA + (size_t)16384*256;
  ushort* Hb0   = slabB + (size_t)4096*256;
  ushort* Hb1   = Hb0 + (size_t)1024*256;
  float*  Cb    = (float*)(Hb1 + (size_t)1024*256);

  init_kernel  <<<1, 64, 0, stream>>>((int*)d_ws);
  detect_kernel<<<16, 256, 0, stream>>>((int*)d_ws, (const uint4*)W_ih);
  z1_kernel    <<<4, 256, 0, stream>>>(wsf, W_ih, b_ih, b_hh, bt, linit);
  prep_kernel  <<<128, 256, 0, stream>>>(wsf, W_ih, W_hh, Wc, Wt);
  ewc_kernel   <<<NVOCAB, 256, 0, stream>>>(wsf, Wc, bc, emb);
  h1_kernel    <<<1, 256, 0, stream>>>(wsf);
  hh1_kernel   <<<5, 256, 0, stream>>>(wsf, W_hh, Wc);
  tag8_kernel  <<<2, 256, 0, stream>>>(wsf);
  p8_kernel    <<<32, 64, 0, stream>>>(wsf);

  // L7 child-prefix tables: (h2,c2)[26] -> HH2A[26] -> (h3,c3)[676] -> HH3[676]
  t2tab_kernel <<<NVOCAB, 256, 0, stream>>>(wsf);
  hhmat_kernel <<<32, 64, 0, stream>>>(wsf, (const ushort*)(wsf+OFF_H2B), wsf+OFF_HH2A, NVOCAB);
  t3tab_kernel <<<NVOCAB*NVOCAB, 256, 0, stream>>>(wsf);
  hhmat_kernel <<<((NVOCAB*NVOCAB+15)/16)*16, 64, 0, stream>>>(wsf, (const ushort*)(wsf+OFF_H3B), wsf+OFF_HH3, NVOCAB*NVOCAB);

  // big levels
  level7_kernel        <<<1024,1024,0,stream>>>(wsf, idents, 5461, 21845, 16384, 65536, slabA);
  level_kernel<1,false><<<256 ,1024,0,stream>>>(wsf, slabA, idents, 1365, 0, 4096, 0, slabB);

  // small levels: M-parallel stepped path (4 steps + fin per level)
  struct Lv { int n, offL; ushort *P, *O; };
  const Lv lv[6] = {
    {1024, 341, slabB, slabA},
    { 256,  85, slabA, slabB},
    {  64,  21, slabB, slabA},
    {  16,   5, slabA, slabB},
    {   4,   1, slabB, slabA},
    {   1,   0, slabA, nullptr},
  };
  for (int i=0; i<6; i++){
    int nt = (lv[i].n + 15) / 16;
    dim3 gs(nt*16);
    step_kernel<true ><<<gs, 64, 0, stream>>>(wsf, lv[i].P, nullptr, Hb1, Cb, lv[i].n, 0);
    step_kernel<false><<<gs, 64, 0, stream>>>(wsf, lv[i].P, Hb1, Hb0, Cb, lv[i].n, 1);
    step_kernel<false><<<gs, 64, 0, stream>>>(wsf, lv[i].P, Hb0, Hb1, Cb, lv[i].n, 2);
    step_kernel<false><<<gs, 64, 0, stream>>>(wsf, lv[i].P, Hb1, Hb0, Cb, lv[i].n, 3);
    if (i < 5) fin_kernel<false><<<nt, 256, 0, stream>>>(wsf, Hb0, idents, lv[i].offL, lv[i].n, lv[i].O, nullptr);
    else       fin_kernel<true ><<<1,  256, 0, stream>>>(wsf, Hb0, idents, 0, 1, nullptr, d_out);
  }
}

// Round 12
// 481.042 us; speedup vs baseline: 1.2561x; 1.0726x over previous
//
#include <hip/hip_runtime.h>
#include <hip/hip_bf16.h>
#include <cstdint>
#include <cstddef>

typedef __hip_bfloat16 bf16;
typedef unsigned short ushort;
typedef __attribute__((ext_vector_type(8))) short bf16x8;
typedef __attribute__((ext_vector_type(4))) float f32x4;

#define HDIM 256
#define NVOCAB 26
#define STR 264

// ---- workspace layout (float offsets) ----
#define OFF_BSUM  16
#define OFF_Z1    (OFF_BSUM+1024)
#define OFF_HH1   (OFF_Z1+1024)
#define OFF_H1    (OFF_HH1+1024)
#define OFF_C1    (OFF_H1+256)
#define OFF_WCH1  (OFF_C1+256)
#define OFF_BTF   (OFF_WCH1+256)
#define OFF_EWC   (OFF_BTF+256)          // [26][256] f32
#define OFF_P8    (OFF_EWC+6656)         // [26][1024] f32
#define OFF_SCB   (OFF_P8+26624)         // [32][256] ushort (scomb bf16)
#define OFF_O8B   (OFF_SCB+4096)         // [32][256] ushort (out8 bf16)
#define OFF_H2B   (OFF_O8B+4096)         // [32][256] ushort (h2 per child0-id)
#define OFF_C2T   (OFF_H2B+4096)         // [32][256] f32
#define OFF_HH2A  (OFF_C2T+8192)         // [32][1024] f32 (bsum + W_hh@h2)
#define OFF_H3B   (OFF_HH2A+32768)       // [704][256] ushort (h3 per (id0,id1))
#define OFF_C3T   (OFF_H3B+90112)        // [704][256] f32
#define OFF_HH3   (OFF_C3T+180224)       // [704][1024] f32 (bsum + W_hh@h3)
#define OFF_FRAG  (OFF_HH3+720896)       // ushort frag tables
#define OFF_SLABS (OFF_FRAG+327680)

__device__ __forceinline__ float sigmf(float x){ return 1.0f/(1.0f+__expf(-x)); }
__device__ __forceinline__ float tanhfast(float x){ return 1.0f - 2.0f/(__expf(2.0f*x)+1.0f); }
__device__ __forceinline__ ushort f2b(float x){ bf16 h = __float2bfloat16(x); return *(ushort*)&h; }
__device__ __forceinline__ float ldin(const void* p, int i, int f32){
  if (f32) return ((const float*)p)[i];
  unsigned int w = ((unsigned int)((const ushort*)p)[i]) << 16;
  return __uint_as_float(w);
}
__device__ __forceinline__ void ld8(const void* p, int i, int f32, float* o){
  if (f32){
    float4 a = *(const float4*)((const float*)p + i);
    float4 b = *(const float4*)((const float*)p + i + 4);
    o[0]=a.x;o[1]=a.y;o[2]=a.z;o[3]=a.w;o[4]=b.x;o[5]=b.y;o[6]=b.z;o[7]=b.w;
  } else {
    uint4 u = *(const uint4*)((const ushort*)p + i);
    unsigned w0=u.x,w1=u.y,w2=u.z,w3=u.w;
    o[0]=__uint_as_float(w0<<16); o[1]=__uint_as_float(w0&0xFFFF0000u);
    o[2]=__uint_as_float(w1<<16); o[3]=__uint_as_float(w1&0xFFFF0000u);
    o[4]=__uint_as_float(w2<<16); o[5]=__uint_as_float(w2&0xFFFF0000u);
    o[6]=__uint_as_float(w3<<16); o[7]=__uint_as_float(w3&0xFFFF0000u);
  }
}
__device__ __forceinline__ uint4 pack8(const ushort* h){
  uint4 u;
  u.x = (unsigned)h[0] | ((unsigned)h[1]<<16);
  u.y = (unsigned)h[2] | ((unsigned)h[3]<<16);
  u.z = (unsigned)h[4] | ((unsigned)h[5]<<16);
  u.w = (unsigned)h[6] | ((unsigned)h[7]<<16);
  return u;
}

__global__ void init_kernel(int* wsI){ if (threadIdx.x<4) wsI[threadIdx.x]=0; }

__global__ __launch_bounds__(256) void detect_kernel(int* wsI, const uint4* wih4){
  int c=0;
  for (int i = blockIdx.x*blockDim.x + threadIdx.x; i < 32768; i += gridDim.x*blockDim.x){
    uint4 u = wih4[i];
    unsigned w[4] = {u.x,u.y,u.z,u.w};
    #pragma unroll
    for (int j=0;j<4;j++){
      if ((w[j] & 0x7F80u) == 0x7F80u) c++;
      if ((w[j] & 0x7F800000u) == 0x7F800000u) c++;
    }
  }
  #pragma unroll
  for (int o=32;o>0;o>>=1) c += __shfl_xor(c,o,64);
  if ((threadIdx.x&63)==0 && c) atomicAdd(&wsI[1], c);
}

__global__ __launch_bounds__(256) void z1_kernel(
    float* __restrict__ wsf, const void* W_ih, const void* b_ih, const void* b_hh,
    const void* bt, const void* linit)
{
  const int f32 = ((const int*)wsf)[1] != 0;
  __shared__ float sx[256];
  int tid = threadIdx.x;
  int r = blockIdx.x*256 + tid;
  sx[tid] = ldin(linit, tid, f32);
  __syncthreads();
  float a = ldin(b_ih, r, f32) + ldin(b_hh, r, f32);
  wsf[OFF_BSUM + r] = a;
  float z = a;
  #pragma unroll 8
  for (int k=0;k<256;k+=8){
    float w[8]; ld8(W_ih, r*256+k, f32, w);
    #pragma unroll
    for (int j=0;j<8;j++) z += w[j]*sx[k+j];
  }
  wsf[OFF_Z1 + r] = z;
  if (blockIdx.x==0) wsf[OFF_BTF + tid] = ldin(bt, tid, f32);
}

__global__ __launch_bounds__(256) void h1_kernel(float* __restrict__ wsf){
  int e = threadIdx.x;
  float zi = wsf[OFF_Z1+e], zg = wsf[OFF_Z1+512+e], zo = wsf[OFF_Z1+768+e];
  float c1 = sigmf(zi)*tanhfast(zg);
  float h1 = sigmf(zo)*tanhfast(c1);
  wsf[OFF_H1+e]=h1; wsf[OFF_C1+e]=c1;
}

// blocks 0..3: hh1 rows; block 4: wch1 + scomb bf16 rows (needs EWC done)
__global__ __launch_bounds__(256) void hh1_kernel(float* __restrict__ wsf, const void* W_hh, const void* Wc){
  const int f32 = ((const int*)wsf)[1] != 0;
  __shared__ float sh1[256];
  int tid = threadIdx.x;
  sh1[tid] = wsf[OFF_H1+tid];
  __syncthreads();
  if (blockIdx.x < 4){
    int r = blockIdx.x*256 + tid;
    float z = wsf[OFF_BSUM + r];
    #pragma unroll 8
    for (int k=0;k<256;k+=8){
      float w[8]; ld8(W_hh, r*256+k, f32, w);
      #pragma unroll
      for (int j=0;j<8;j++) z += w[j]*sh1[k+j];
    }
    wsf[OFF_HH1 + r] = z;
  } else {
    float a = 0.f;
    #pragma unroll 8
    for (int k=0;k<256;k+=8){
      float w[8]; ld8(Wc, tid*512+k, f32, w);
      #pragma unroll
      for (int j=0;j<8;j++) a += w[j]*sh1[k+j];
    }
    wsf[OFF_WCH1 + tid] = a;
    ushort* SCB = (ushort*)(wsf + OFF_SCB);
    #pragma unroll 1
    for (int v32=0; v32<32; v32++){
      int v = v32 < NVOCAB ? v32 : NVOCAB-1;
      SCB[v32*256 + tid] = f2b(a + wsf[OFF_EWC + v*256 + tid]);
    }
  }
}

__global__ __launch_bounds__(256) void ewc_kernel(
    float* __restrict__ wsf, const void* Wc, const void* bc, const void* emb)
{
  const int f32 = ((const int*)wsf)[1] != 0;
  int v = blockIdx.x, i = threadIdx.x;
  __shared__ float se[256];
  se[i] = ldin(emb, v*256+i, f32);
  __syncthreads();
  float a = ldin(bc, i, f32);
  #pragma unroll 8
  for (int k=0;k<256;k+=8){
    float w[8]; ld8(Wc, i*512+256+k, f32, w);
    #pragma unroll
    for (int j=0;j<8;j++) a += w[j]*se[k+j];
  }
  wsf[OFF_EWC + v*256 + i] = a;
}

// A-fragment tables, vectorized: thread handles 8 consecutive k (one 16B store)
__global__ __launch_bounds__(256) void prep_kernel(
    float* __restrict__ wsf, const void* W_ih, const void* W_hh, const void* Wc, const void* Wt)
{
  const int f32 = ((const int*)wsf)[1] != 0;
  ushort* FWIH = (ushort*)(wsf + OFF_FRAG);
  ushort* FWHH = FWIH + 262144;
  ushort* FWC1 = FWHH + 262144;
  ushort* FWT  = FWC1 + 65536;
  int stride = gridDim.x*blockDim.x;
  int t0 = blockIdx.x*blockDim.x + threadIdx.x;
  for (int i=t0; i<32768; i+=stride){
    int c = i >> 6, L = i & 63;
    int mt = c>>3, ks = c&7;
    int m = (mt<<4) | (L&15);
    int k0 = (ks<<5) + ((L>>4)<<3);
    float w[8]; ushort h[8];
    ld8(W_ih, m*256+k0, f32, w);
    #pragma unroll
    for (int j=0;j<8;j++) h[j]=f2b(w[j]);
    *(uint4*)&FWIH[(c<<9)+(L<<3)] = pack8(h);
    ld8(W_hh, m*256+k0, f32, w);
    #pragma unroll
    for (int j=0;j<8;j++) h[j]=f2b(w[j]);
    *(uint4*)&FWHH[(c<<9)+(L<<3)] = pack8(h);
  }
  for (int i=t0; i<8192; i+=stride){
    int c = i >> 6, L = i & 63;
    int mt = c>>3, ks = c&7;
    int m = (mt<<4) | (L&15);
    int k0 = (ks<<5) + ((L>>4)<<3);
    float w[8]; ushort h[8];
    ld8(Wc, m*512+k0, f32, w);
    #pragma unroll
    for (int j=0;j<8;j++) h[j]=f2b(w[j]);
    *(uint4*)&FWC1[(c<<9)+(L<<3)] = pack8(h);
    ld8(Wt, m*256+k0, f32, w);
    #pragma unroll
    for (int j=0;j<8;j++) h[j]=f2b(w[j]);
    *(uint4*)&FWT[(c<<9)+(L<<3)] = pack8(h);
  }
}

// ---- tag8: tag = Wt@scomb + bt, log-softmax, out8 bf16 rows (26 vocab) ----
__global__ __launch_bounds__(256) void tag8_kernel(float* __restrict__ wsf){
  __shared__ float wred[4][16];
  const int tid=threadIdx.x, wv=tid>>6, lane=tid&63, ln15=lane&15, quad=lane>>4;
  const int nt = blockIdx.x;
  const ushort* FWT = (const ushort*)(wsf + OFF_FRAG) + 262144 + 262144 + 65536;
  const ushort* SCB = (const ushort*)(wsf + OFF_SCB);
  ushort* O8B = (ushort*)(wsf + OFF_O8B);
  const int row = nt*16 + ln15;

  f32x4 tg[4];
  #pragma unroll 1
  for (int p=0; p<4; p++){
    const int mt = wv*4 + p;
    tg[p] = (f32x4){0.f,0.f,0.f,0.f};
    #pragma unroll
    for (int ks=0; ks<8; ks++){
      bf16x8 a = *(const bf16x8*)&FWT[((mt*8+ks)<<9) + (lane<<3)];
      bf16x8 b = *(const bf16x8*)&SCB[row*256 + ks*32 + quad*8];
      tg[p] = __builtin_amdgcn_mfma_f32_16x16x32_bf16(a, b, tg[p], 0,0,0);
    }
    float4 bt4 = *(const float4*)&wsf[OFF_BTF + mt*16 + quad*4];
    #pragma unroll
    for (int r=0; r<4; r++) tg[p][r] += ((const float*)&bt4)[r];
  }

  float mx = -3.0e38f;
  #pragma unroll
  for (int p=0; p<4; p++)
    #pragma unroll
    for (int r=0; r<4; r++) mx = fmaxf(mx, tg[p][r]);
  mx = fmaxf(mx, __shfl_xor(mx, 16, 64));
  mx = fmaxf(mx, __shfl_xor(mx, 32, 64));
  wred[wv][ln15] = mx;
  __syncthreads();
  float gmx = fmaxf(fmaxf(wred[0][ln15], wred[1][ln15]), fmaxf(wred[2][ln15], wred[3][ln15]));
  __syncthreads();
  float s = 0.f;
  #pragma unroll
  for (int p=0; p<4; p++)
    #pragma unroll
    for (int r=0; r<4; r++) s += __expf(tg[p][r] - gmx);
  s += __shfl_xor(s, 16, 64);
  s += __shfl_xor(s, 32, 64);
  wred[wv][ln15] = s;
  __syncthreads();
  float gs = (wred[0][ln15]+wred[1][ln15]) + (wred[2][ln15]+wred[3][ln15]);
  float lz = gmx + __logf(gs);

  #pragma unroll
  for (int p=0; p<4; p++){
    int m = (wv*4+p)*16 + quad*4;
    ushort ob[4];
    #pragma unroll
    for (int r=0; r<4; r++) ob[r] = f2b(tg[p][r] - lz);
    uint2 uu;
    uu.x = (unsigned)ob[0] | ((unsigned)ob[1]<<16);
    uu.y = (unsigned)ob[2] | ((unsigned)ob[3]<<16);
    *(uint2*)&O8B[row*256 + m] = uu;
  }
}

// ---- p8: P8[v] = W_ih @ out8[v] via MFMA ----
__global__ __launch_bounds__(64) void p8_kernel(float* __restrict__ wsf){
  const int nt = blockIdx.x >> 4, eb = blockIdx.x & 15;
  const int lane = threadIdx.x, ln15 = lane & 15, quad = lane >> 4;
  const ushort* FWIH = (const ushort*)(wsf + OFF_FRAG);
  const ushort* O8B  = (const ushort*)(wsf + OFF_O8B);
  const int row = nt*16 + ln15;

  f32x4 acc[4];
  #pragma unroll
  for (int g=0; g<4; g++) acc[g] = (f32x4){0.f,0.f,0.f,0.f};
  #pragma unroll
  for (int ks=0; ks<8; ks++){
    bf16x8 b = *(const bf16x8*)&O8B[row*256 + ks*32 + quad*8];
    #pragma unroll
    for (int g=0; g<4; g++){
      int mt = g*16 + eb;
      bf16x8 a = *(const bf16x8*)&FWIH[((mt*8+ks)<<9) + (lane<<3)];
      acc[g] = __builtin_amdgcn_mfma_f32_16x16x32_bf16(a, b, acc[g], 0,0,0);
    }
  }
  if (row < NVOCAB){
    #pragma unroll
    for (int g=0; g<4; g++)
      *(float4*)&wsf[OFF_P8 + row*1024 + g*256 + eb*16 + quad*4] =
        (float4){acc[g][0], acc[g][1], acc[g][2], acc[g][3]};
  }
}

// ---- t2 table: (h2,c2)[a] = gate(hh1 + P8[a], cp=C1), a<26 ----
__global__ __launch_bounds__(256) void t2tab_kernel(float* __restrict__ wsf){
  int a = blockIdx.x, e = threadIdx.x;
  const float* P8a = wsf + OFF_P8 + (size_t)a*1024;
  float zi = wsf[OFF_HH1+e]     + P8a[e];
  float zf = wsf[OFF_HH1+256+e] + P8a[256+e];
  float zg = wsf[OFF_HH1+512+e] + P8a[512+e];
  float zo = wsf[OFF_HH1+768+e] + P8a[768+e];
  float cn = sigmf(zf)*wsf[OFF_C1+e] + sigmf(zi)*tanhfast(zg);
  ((ushort*)(wsf+OFF_H2B))[a*256+e] = f2b(sigmf(zo)*tanhfast(cn));
  wsf[OFF_C2T + a*256 + e] = cn;
}

// ---- hhmat: Out[r] = bsum + W_hh @ Hrows[r]  (MFMA) ----
__global__ __launch_bounds__(64) void hhmat_kernel(
    float* __restrict__ wsf, const ushort* __restrict__ Hrows,
    float* __restrict__ Out, int R)
{
  const int nt = blockIdx.x >> 4, eb = blockIdx.x & 15;
  const int lane = threadIdx.x, ln15 = lane & 15, quad = lane >> 4;
  const ushort* FWHH = (const ushort*)(wsf + OFF_FRAG) + 262144;
  int row = nt*16 + ln15;
  int rowc = row < R ? row : R-1;

  f32x4 acc[4];
  #pragma unroll
  for (int g=0; g<4; g++) acc[g] = (f32x4){0.f,0.f,0.f,0.f};
  #pragma unroll
  for (int ks=0; ks<8; ks++){
    bf16x8 b = *(const bf16x8*)&Hrows[rowc*256 + ks*32 + quad*8];
    #pragma unroll
    for (int g=0; g<4; g++){
      int mt = g*16 + eb;
      bf16x8 a = *(const bf16x8*)&FWHH[((mt*8+ks)<<9) + (lane<<3)];
      acc[g] = __builtin_amdgcn_mfma_f32_16x16x32_bf16(a, b, acc[g], 0,0,0);
    }
  }
  if (row < R){
    #pragma unroll
    for (int g=0; g<4; g++){
      int m = g*256 + eb*16 + quad*4;
      float4 bs = *(const float4*)&wsf[OFF_BSUM + m];
      *(float4*)&Out[(size_t)row*1024 + m] =
        (float4){acc[g][0]+bs.x, acc[g][1]+bs.y, acc[g][2]+bs.z, acc[g][3]+bs.w};
    }
  }
}

// ---- t3 table: (h3,c3)[a*26+b] = gate(HH2A[a] + P8[b], cp=C2[a]) ----
__global__ __launch_bounds__(256) void t3tab_kernel(float* __restrict__ wsf){
  int p = blockIdx.x;
  int a = p / 26, b = p - a*26;
  int e = threadIdx.x;
  const float* HA = wsf + OFF_HH2A + (size_t)a*1024;
  const float* PB = wsf + OFF_P8   + (size_t)b*1024;
  float zi = HA[e]     + PB[e];
  float zf = HA[256+e] + PB[256+e];
  float zg = HA[512+e] + PB[512+e];
  float zo = HA[768+e] + PB[768+e];
  float cn = sigmf(zf)*wsf[OFF_C2T + a*256 + e] + sigmf(zi)*tanhfast(zg);
  ((ushort*)(wsf+OFF_H3B))[p*256+e] = f2b(sigmf(zo)*tanhfast(cn));
  wsf[OFF_C3T + p*256 + e] = cn;
}

// ---- level-7 kernel: t1/t2 tabulated; t3 = gather-gate, t4 = one W_hh MFMA ----
__global__ __launch_bounds__(1024) void level7_kernel(
    const float* __restrict__ wsf, const int* __restrict__ idents,
    int offL, int offC, int nNodes, int nChild, ushort* __restrict__ OutNext)
{
  __shared__ __align__(16) ushort Hlds[2][16*STR];
  __shared__ float wred[16][16];
  __shared__ int sid[16], sid4[64];
  const int tid=threadIdx.x, wv=tid>>6, lane=tid&63, ln15=lane&15, quad=lane>>4;
  const int j0 = blockIdx.x*16;
  const ushort* FWHH = (const ushort*)(wsf+OFF_FRAG)+262144;
  const ushort* FWC1 = FWHH+262144;
  const ushort* FWT  = FWC1+65536;
  const float* P8 = wsf+OFF_P8;
  const float* EWcP = wsf+OFF_EWC;

  if (tid<16){ int nd=j0+tid; if(nd>=nNodes) nd=nNodes-1; sid[tid]=idents[offL+nd]; }
  if (tid<64){ int ci=j0*4+tid; if(ci>=nChild) ci=nChild-1; sid4[tid]=idents[offC+ci]; }
  __syncthreads();

  const int eb = wv*16;
  const int ia=sid4[ln15*4], ib=sid4[ln15*4+1], ic=sid4[ln15*4+2], idd=sid4[ln15*4+3];
  const int pp = ia*26+ib;

  f32x4 creg;
  // t3: z = HH3[pp] + P8[ic], cp = C3[pp]  (no MFMA)
  {
    const float* HH3p = wsf + OFF_HH3 + (size_t)pp*1024;
    const float* P8c  = P8 + (size_t)ic*1024;
    float4 cp4 = *(const float4*)&wsf[OFF_C3T + (size_t)pp*256 + eb + quad*4];
    float z[4][4];
    #pragma unroll
    for (int g=0; g<4; g++){
      float4 hv = *(const float4*)&HH3p[g*256 + eb + quad*4];
      float4 pv = *(const float4*)&P8c[g*256 + eb + quad*4];
      z[g][0]=hv.x+pv.x; z[g][1]=hv.y+pv.y; z[g][2]=hv.z+pv.z; z[g][3]=hv.w+pv.w;
    }
    ushort hb[4];
    #pragma unroll
    for (int r=0; r<4; r++){
      float cn = sigmf(z[1][r])*((const float*)&cp4)[r] + sigmf(z[0][r])*tanhfast(z[2][r]);
      creg[r]=cn;
      hb[r]=f2b(sigmf(z[3][r])*tanhfast(cn));
    }
    uint2 uu;
    uu.x = (unsigned)hb[0] | ((unsigned)hb[1]<<16);
    uu.y = (unsigned)hb[2] | ((unsigned)hb[3]<<16);
    *(uint2*)&Hlds[0][ln15*STR + eb + quad*4] = uu;
  }
  __syncthreads();

  // t4: z = W_hh@h4 + bsum + P8[idd]
  {
    f32x4 acc[4];
    #pragma unroll
    for (int g=0; g<4; g++) acc[g] = (f32x4){0.f,0.f,0.f,0.f};
    #pragma unroll
    for (int ks=0; ks<8; ks++){
      bf16x8 bh = *(const bf16x8*)&Hlds[0][ln15*STR + ks*32 + quad*8];
      #pragma unroll
      for (int g=0; g<4; g++){
        bf16x8 a = *(const bf16x8*)&FWHH[(((g*16+wv)*8+ks)<<9) + (lane<<3)];
        acc[g] = __builtin_amdgcn_mfma_f32_16x16x32_bf16(a, bh, acc[g], 0,0,0);
      }
    }
    const float* P8d = P8 + (size_t)idd*1024;
    #pragma unroll
    for (int g=0; g<4; g++){
      float4 bg = *(const float4*)&wsf[OFF_BSUM + g*256 + eb + quad*4];
      float4 xg = *(const float4*)&P8d[g*256 + eb + quad*4];
      acc[g][0]+=bg.x+xg.x; acc[g][1]+=bg.y+xg.y; acc[g][2]+=bg.z+xg.z; acc[g][3]+=bg.w+xg.w;
    }
    ushort hb[4];
    #pragma unroll
    for (int r=0; r<4; r++){
      float cn = sigmf(acc[1][r])*creg[r] + sigmf(acc[0][r])*tanhfast(acc[2][r]);
      hb[r]=f2b(sigmf(acc[3][r])*tanhfast(cn));
    }
    uint2 uu;
    uu.x = (unsigned)hb[0] | ((unsigned)hb[1]<<16);
    uu.y = (unsigned)hb[2] | ((unsigned)hb[3]<<16);
    *(uint2*)&Hlds[1][ln15*STR + eb + quad*4] = uu;
  }
  __syncthreads();

  // combine = Wc1@h5 + EWc[id]  (h5 in Hlds[1] -> comb in Hlds[0])
  {
    f32x4 ac = (f32x4){0.f,0.f,0.f,0.f};
    #pragma unroll
    for (int ks=0; ks<8; ks++){
      bf16x8 a = *(const bf16x8*)&FWC1[((wv*8+ks)<<9) + (lane<<3)];
      bf16x8 b = *(const bf16x8*)&Hlds[1][ln15*STR + ks*32 + quad*8];
      ac = __builtin_amdgcn_mfma_f32_16x16x32_bf16(a, b, ac, 0,0,0);
    }
    float4 ew = *(const float4*)&EWcP[(size_t)sid[ln15]*256 + wv*16 + quad*4];
    ushort cb[4];
    #pragma unroll
    for (int r=0; r<4; r++) cb[r] = f2b(ac[r] + ((const float*)&ew)[r]);
    uint2 uu;
    uu.x = (unsigned)cb[0] | ((unsigned)cb[1]<<16);
    uu.y = (unsigned)cb[2] | ((unsigned)cb[3]<<16);
    *(uint2*)&Hlds[0][ln15*STR + wv*16 + quad*4] = uu;
  }
  __syncthreads();

  // tag = Wt@comb + bt
  f32x4 tg = (f32x4){0.f,0.f,0.f,0.f};
  #pragma unroll
  for (int ks=0; ks<8; ks++){
    bf16x8 a = *(const bf16x8*)&FWT[((wv*8+ks)<<9) + (lane<<3)];
    bf16x8 b = *(const bf16x8*)&Hlds[0][ln15*STR + ks*32 + quad*8];
    tg = __builtin_amdgcn_mfma_f32_16x16x32_bf16(a, b, tg, 0,0,0);
  }
  {
    float4 bt4 = *(const float4*)&wsf[OFF_BTF + wv*16 + quad*4];
    #pragma unroll
    for (int r=0; r<4; r++) tg[r] += ((const float*)&bt4)[r];
  }

  // log-softmax over 256 rows (16 wave partials)
  float mx = fmaxf(fmaxf(tg[0],tg[1]), fmaxf(tg[2],tg[3]));
  mx = fmaxf(mx, __shfl_xor(mx, 16, 64));
  mx = fmaxf(mx, __shfl_xor(mx, 32, 64));
  wred[wv][ln15] = mx;
  __syncthreads();
  float gmx = wred[0][ln15];
  #pragma unroll
  for (int w=1; w<16; w++) gmx = fmaxf(gmx, wred[w][ln15]);
  __syncthreads();
  float s = __expf(tg[0]-gmx) + __expf(tg[1]-gmx) + __expf(tg[2]-gmx) + __expf(tg[3]-gmx);
  s += __shfl_xor(s, 16, 64);
  s += __shfl_xor(s, 32, 64);
  wred[wv][ln15] = s;
  __syncthreads();
  float gs = 0.f;
  #pragma unroll
  for (int w=0; w<16; w++) gs += wred[w][ln15];
  float lz = gmx + __logf(gs);

  int node = j0 + ln15;
  if (node < nNodes){
    ushort ob[4];
    #pragma unroll
    for (int r=0; r<4; r++) ob[r] = f2b(tg[r] - lz);
    uint2 uu;
    uu.x = (unsigned)ob[0] | ((unsigned)ob[1]<<16);
    uu.y = (unsigned)ob[2] | ((unsigned)ob[3]<<16);
    *(uint2*)&OutNext[(size_t)node*256 + wv*16 + quad*4] = uu;
  }
}

// ---- one LSTM t-step (all levels below 7): M-parallel across the grid ----
template<bool FIRST>
__global__ __launch_bounds__(64) void step_kernel(
    const float* __restrict__ wsf, const ushort* __restrict__ OutPrev,
    const ushort* __restrict__ Hin, ushort* __restrict__ Hout,
    float* __restrict__ Cbuf, int nNodes, int tm1)
{
  const int nt   = blockIdx.x >> 4;
  const int eb   = blockIdx.x & 15;
  const int lane = threadIdx.x;
  const int ln15 = lane & 15;
  const int quad = lane >> 4;

  const ushort* FWIH = (const ushort*)(wsf + OFF_FRAG);
  const ushort* FWHH = FWIH + 262144;

  int node = nt*16 + ln15; if (node >= nNodes) node = nNodes-1;
  const int rowX = (node*4 + tm1) * 256;
  const int rowH = node * 256;

  f32x4 acc[4];
  #pragma unroll
  for (int g=0; g<4; g++) acc[g] = (f32x4){0.f,0.f,0.f,0.f};

  #pragma unroll
  for (int ks=0; ks<8; ks++){
    bf16x8 bx = *(const bf16x8*)&OutPrev[rowX + ks*32 + quad*8];
    bf16x8 bh;
    if (!FIRST) bh = *(const bf16x8*)&Hin[rowH + ks*32 + quad*8];
    #pragma unroll
    for (int g=0; g<4; g++){
      int mt = g*16 + eb;
      bf16x8 a = *(const bf16x8*)&FWIH[((mt*8+ks)<<9) + (lane<<3)];
      acc[g] = __builtin_amdgcn_mfma_f32_16x16x32_bf16(a, bx, acc[g], 0,0,0);
      if (!FIRST){
        bf16x8 a2 = *(const bf16x8*)&FWHH[((mt*8+ks)<<9) + (lane<<3)];
        acc[g] = __builtin_amdgcn_mfma_f32_16x16x32_bf16(a2, bh, acc[g], 0,0,0);
      }
    }
  }

  const float* baseP = wsf + (FIRST ? OFF_HH1 : OFF_BSUM);
  const int e0 = eb*16 + quad*4;
  float4 b0 = *(const float4*)&baseP[       e0];
  float4 b1 = *(const float4*)&baseP[ 256 + e0];
  float4 b2 = *(const float4*)&baseP[ 512 + e0];
  float4 b3 = *(const float4*)&baseP[ 768 + e0];
  float4 cp;
  if (FIRST) cp = *(const float4*)&wsf[OFF_C1 + e0];
  else       cp = *(const float4*)&Cbuf[rowH + e0];

  float cn4[4]; ushort hb[4];
  #pragma unroll
  for (int r=0; r<4; r++){
    float zi = acc[0][r] + ((const float*)&b0)[r];
    float zf = acc[1][r] + ((const float*)&b1)[r];
    float zg = acc[2][r] + ((const float*)&b2)[r];
    float zo = acc[3][r] + ((const float*)&b3)[r];
    float cn = sigmf(zf)*((const float*)&cp)[r] + sigmf(zi)*tanhfast(zg);
    cn4[r] = cn;
    hb[r] = f2b(sigmf(zo)*tanhfast(cn));
  }
  *(float4*)&Cbuf[rowH + e0] = (float4){cn4[0],cn4[1],cn4[2],cn4[3]};
  uint2 uu;
  uu.x = (unsigned)hb[0] | ((unsigned)hb[1]<<16);
  uu.y = (unsigned)hb[2] | ((unsigned)hb[3]<<16);
  *(uint2*)&Hout[rowH + e0] = uu;
}

// ---- epilogue for step levels: combine -> tag -> log-softmax -> out ----
template<bool FINAL>
__global__ __launch_bounds__(256) void fin_kernel(
    const float* __restrict__ wsf, const ushort* __restrict__ Hfin,
    const int* __restrict__ idents, int offL, int nNodes,
    ushort* __restrict__ OutNext, void* __restrict__ dout)
{
  __shared__ __align__(16) ushort Clds[16*STR];
  __shared__ float wred[4][16];
  const int tid  = threadIdx.x;
  const int wv   = tid >> 6;
  const int lane = tid & 63;
  const int ln15 = lane & 15;
  const int quad = lane >> 4;
  const int nt   = blockIdx.x;

  const ushort* FWIH = (const ushort*)(wsf + OFF_FRAG);
  const ushort* FWC1 = FWIH + 262144 + 262144;
  const ushort* FWT  = FWC1 + 65536;
  const float*  EWcP = wsf + OFF_EWC;

  int node = nt*16 + ln15; if (node >= nNodes) node = nNodes-1;
  const int myid = idents[offL + node];
  const int rowH = node * 256;

  #pragma unroll 1
  for (int p=0; p<4; p++){
    const int mt = wv*4 + p;
    f32x4 ac = (f32x4){0.f,0.f,0.f,0.f};
    #pragma unroll
    for (int ks=0; ks<8; ks++){
      bf16x8 a = *(const bf16x8*)&FWC1[((mt*8+ks)<<9) + (lane<<3)];
      bf16x8 b = *(const bf16x8*)&Hfin[rowH + ks*32 + quad*8];
      ac = __builtin_amdgcn_mfma_f32_16x16x32_bf16(a, b, ac, 0,0,0);
    }
    float4 ew = *(const float4*)&EWcP[(size_t)myid*256 + mt*16 + quad*4];
    ushort cb[4];
    #pragma unroll
    for (int r=0; r<4; r++) cb[r] = f2b(ac[r] + ((const float*)&ew)[r]);
    uint2 uu;
    uu.x = (unsigned)cb[0] | ((unsigned)cb[1]<<16);
    uu.y = (unsigned)cb[2] | ((unsigned)cb[3]<<16);
    *(uint2*)&Clds[ln15*STR + mt*16 + quad*4] = uu;
  }
  __syncthreads();

  f32x4 tg[4];
  #pragma unroll 1
  for (int p=0; p<4; p++){
    const int mt = wv*4 + p;
    tg[p] = (f32x4){0.f,0.f,0.f,0.f};
    #pragma unroll
    for (int ks=0; ks<8; ks++){
      bf16x8 a = *(const bf16x8*)&FWT[((mt*8+ks)<<9) + (lane<<3)];
      bf16x8 b = *(const bf16x8*)&Clds[ln15*STR + ks*32 + quad*8];
      tg[p] = __builtin_amdgcn_mfma_f32_16x16x32_bf16(a, b, tg[p], 0,0,0);
    }
    float4 bt4 = *(const float4*)&wsf[OFF_BTF + mt*16 + quad*4];
    #pragma unroll
    for (int r=0; r<4; r++) tg[p][r] += ((const float*)&bt4)[r];
  }

  float mx = -3.0e38f;
  #pragma unroll
  for (int p=0; p<4; p++)
    #pragma unroll
    for (int r=0; r<4; r++) mx = fmaxf(mx, tg[p][r]);
  mx = fmaxf(mx, __shfl_xor(mx, 16, 64));
  mx = fmaxf(mx, __shfl_xor(mx, 32, 64));
  wred[wv][ln15] = mx;
  __syncthreads();
  float gmx = fmaxf(fmaxf(wred[0][ln15], wred[1][ln15]), fmaxf(wred[2][ln15], wred[3][ln15]));
  __syncthreads();
  float s = 0.f;
  #pragma unroll
  for (int p=0; p<4; p++)
    #pragma unroll
    for (int r=0; r<4; r++) s += __expf(tg[p][r] - gmx);
  s += __shfl_xor(s, 16, 64);
  s += __shfl_xor(s, 32, 64);
  wred[wv][ln15] = s;
  __syncthreads();
  float gs = (wred[0][ln15]+wred[1][ln15]) + (wred[2][ln15]+wred[3][ln15]);
  float lz = gmx + __logf(gs);

  if (FINAL){
    if (ln15 == 0){
      const int f32o = ((const int*)wsf)[1] != 0;
      #pragma unroll
      for (int p=0; p<4; p++){
        #pragma unroll
        for (int r=0; r<4; r++){
          int m = (wv*4+p)*16 + quad*4 + r;
          float v = tg[p][r] - lz;
          if (f32o) ((float*)dout)[m] = v;
          else      ((ushort*)dout)[m] = f2b(v);
        }
      }
    }
    return;
  }
  int onode = nt*16 + ln15;
  if (onode < nNodes){
    #pragma unroll
    for (int p=0; p<4; p++){
      int m = (wv*4+p)*16 + quad*4;
      ushort ob[4];
      #pragma unroll
      for (int r=0; r<4; r++) ob[r] = f2b(tg[p][r] - lz);
      uint2 uu;
      uu.x = (unsigned)ob[0] | ((unsigned)ob[1]<<16);
      uu.y = (unsigned)ob[2] | ((unsigned)ob[3]<<16);
      *(uint2*)&OutNext[(size_t)onode*256 + m] = uu;
    }
  }
}

extern "C" void kernel_launch(void* const* d_in, const int* in_sizes, int n_in,
                              void* d_out, int out_size, void* d_ws, size_t ws_size,
                              hipStream_t stream)
{
  (void)in_sizes; (void)n_in; (void)out_size; (void)ws_size;
  const int* idents = (const int*)d_in[0];
  const void* emb   = d_in[1];
  const void* W_ih  = d_in[2];
  const void* W_hh  = d_in[3];
  const void* b_ih  = d_in[4];
  const void* b_hh  = d_in[5];
  const void* Wc    = d_in[6];
  const void* bc    = d_in[7];
  const void* Wt    = d_in[8];
  const void* bt    = d_in[9];
  const void* linit = d_in[10];

  float* wsf = (float*)d_ws;
  ushort* slabA = (ushort*)(wsf + OFF_SLABS);
  ushort* slabB = slabA + (size_t)16384*256;
  ushort* Hb0   = slabB + (size_t)4096*256;      // 4096 rows (L6-sized)
  ushort* Hb1   = Hb0 + (size_t)4096*256;
  float*  Cb    = (float*)(Hb1 + (size_t)4096*256);

  init_kernel  <<<1, 64, 0, stream>>>((int*)d_ws);
  detect_kernel<<<16, 256, 0, stream>>>((int*)d_ws, (const uint4*)W_ih);
  z1_kernel    <<<4, 256, 0, stream>>>(wsf, W_ih, b_ih, b_hh, bt, linit);
  prep_kernel  <<<128, 256, 0, stream>>>(wsf, W_ih, W_hh, Wc, Wt);
  ewc_kernel   <<<NVOCAB, 256, 0, stream>>>(wsf, Wc, bc, emb);
  h1_kernel    <<<1, 256, 0, stream>>>(wsf);
  hh1_kernel   <<<5, 256, 0, stream>>>(wsf, W_hh, Wc);
  tag8_kernel  <<<2, 256, 0, stream>>>(wsf);
  p8_kernel    <<<32, 64, 0, stream>>>(wsf);

  // L7 child-prefix tables: (h2,c2)[26] -> HH2A[26] -> (h3,c3)[676] -> HH3[676]
  t2tab_kernel <<<NVOCAB, 256, 0, stream>>>(wsf);
  hhmat_kernel <<<32, 64, 0, stream>>>(wsf, (const ushort*)(wsf+OFF_H2B), wsf+OFF_HH2A, NVOCAB);
  t3tab_kernel <<<NVOCAB*NVOCAB, 256, 0, stream>>>(wsf);
  hhmat_kernel <<<((NVOCAB*NVOCAB+15)/16)*16, 64, 0, stream>>>(wsf, (const ushort*)(wsf+OFF_H3B), wsf+OFF_HH3, NVOCAB*NVOCAB);

  // L7 (prefix-table kernel)
  level7_kernel<<<1024,1024,0,stream>>>(wsf, idents, 5461, 21845, 16384, 65536, slabA);

  // L6..L0: M-parallel stepped path (4 steps + fin per level)
  struct Lv { int n, offL; ushort *P, *O; };
  const Lv lv[7] = {
    {4096, 1365, slabA, slabB},
    {1024,  341, slabB, slabA},
    { 256,   85, slabA, slabB},
    {  64,   21, slabB, slabA},
    {  16,    5, slabA, slabB},
    {   4,    1, slabB, slabA},
    {   1,    0, slabA, nullptr},
  };
  for (int i=0; i<7; i++){
    int nt = (lv[i].n + 15) / 16;
    dim3 gs(nt*16);
    step_kernel<true ><<<gs, 64, 0, stream>>>(wsf, lv[i].P, nullptr, Hb1, Cb, lv[i].n, 0);
    step_kernel<false><<<gs, 64, 0, stream>>>(wsf, lv[i].P, Hb1, Hb0, Cb, lv[i].n, 1);
    step_kernel<false><<<gs, 64, 0, stream>>>(wsf, lv[i].P, Hb0, Hb1, Cb, lv[i].n, 2);
    step_kernel<false><<<gs, 64, 0, stream>>>(wsf, lv[i].P, Hb1, Hb0, Cb, lv[i].n, 3);
    if (i < 6) fin_kernel<false><<<nt, 256, 0, stream>>>(wsf, Hb0, idents, lv[i].offL, lv[i].n, lv[i].O, nullptr);
    else       fin_kernel<true ><<<1,  256, 0, stream>>>(wsf, Hb0, idents, 0, 1, nullptr, d_out);
  }
}